// Round 7
// baseline (111.377 us; speedup 1.0000x reference)
//
#include <hip/hip_runtime.h>
#include <hip/hip_bf16.h>

#define N 4096
#define HID 256
#define NH 8
#define HD 32
#define NC 784    // 256 Q | 256 K | 256 V | 16 EG
#define CH 8      // j-chunks (ws >= 41 MB proven)
#define JSPAN (N / CH)

typedef __attribute__((ext_vector_type(8))) short short8;
typedef __attribute__((ext_vector_type(4))) short short4v;
typedef __attribute__((ext_vector_type(4))) float f32x4;
typedef __attribute__((ext_vector_type(2))) unsigned int uint2v;
typedef __attribute__((ext_vector_type(4))) unsigned int uint4v;

// Q scale = (1/sqrt(32)) * log2(e): folds softmax temp AND exp->exp2 conversion
#define QSCALE 0.25503482f

static __device__ __forceinline__ unsigned short f2bf(float f) {
    union { float f; unsigned u; } v; v.f = f;
    unsigned r = v.u + 0x7fff + ((v.u >> 16) & 1);
    return (unsigned short)(r >> 16);
}
static __device__ __forceinline__ float bf2f(unsigned short u) {
    union { unsigned u; float f; } v; v.u = ((unsigned)u) << 16; return v.f;
}
static __device__ __forceinline__ unsigned packbf2(float a, float b) {
    __hip_bfloat162 t = __float22bfloat162_rn(make_float2(a, b));
    unsigned u; __builtin_memcpy(&u, &t, 4); return u;
}

// ---- fused prep: feat->bf16 (blocks 0..1023) | WbT/bC build + colS zero ----
__global__ void k_prep(const float* __restrict__ feat, const float* __restrict__ Wq,
                       const float* __restrict__ Wkv, const float* __restrict__ Weg,
                       const float* __restrict__ bq, const float* __restrict__ bkv,
                       const float* __restrict__ beg, unsigned short* __restrict__ featb,
                       unsigned short* __restrict__ WbT, float* __restrict__ bC,
                       float* __restrict__ colS) {
    int bx = blockIdx.x;
    if (bx < 1024) {
        int t = bx * 256 + threadIdx.x;
        float4 v = ((const float4*)feat)[t];
        short4v o;
        o[0] = (short)f2bf(v.x); o[1] = (short)f2bf(v.y);
        o[2] = (short)f2bf(v.z); o[3] = (short)f2bf(v.w);
        ((short4v*)featb)[t] = o;
    } else {
        int c = bx - 1024, k = threadIdx.x;
        float w, b;
        if (c < 256)      { w = Wq[k * 256 + c];          b = bq[c]; }
        else if (c < 768) { w = Wkv[k * 512 + (c - 256)]; b = bkv[c - 256]; }
        else              { w = Weg[k * 16 + (c - 768)];  b = beg[c - 768]; }
        WbT[c * 256 + k] = f2bf(w);
        if (k == 0) bC[c] = b;
        if (c < 128) colS[c * 256 + k] = 0.f;
    }
}

// ---- projection GEMM: [4096,256]x[256,784]; scatter into packed layouts ----
__global__ __launch_bounds__(256) void k_proj(const unsigned short* __restrict__ featb,
                                              const unsigned short* __restrict__ WbT,
                                              const float* __restrict__ bC,
                                              unsigned short* __restrict__ Qp,
                                              unsigned short* __restrict__ Kp,
                                              unsigned short* __restrict__ VpT,
                                              float* __restrict__ sigG) {
    int w = threadIdx.x >> 6, l = threadIdx.x & 63;
    int il = l & 15, g = l >> 4;
    int c0 = blockIdx.x * 16;
    int i0 = (blockIdx.y * 4 + w) * 16;
    const short8* Arow = (const short8*)(featb + (size_t)(i0 + il) * HID);
    const short8* Brow = (const short8*)(WbT + (size_t)(c0 + il) * HID);
    f32x4 acc = {0.f, 0.f, 0.f, 0.f};
#pragma unroll
    for (int k0 = 0; k0 < HID; k0 += 32) {
        short8 a = Arow[(k0 >> 3) + g];
        short8 b = Brow[(k0 >> 3) + g];
        acc = __builtin_amdgcn_mfma_f32_16x16x32_bf16(a, b, acc, 0, 0, 0);
    }
    int c = c0 + il;
    float bias = bC[c];
#pragma unroll
    for (int r = 0; r < 4; ++r) {
        int i = i0 + g * 4 + r;
        float val = acc[r] + bias;
        if (c < 256) {
            int h = c & 7, d = c >> 3;
            Qp[((size_t)h * N + i) * HD + d] = f2bf(val * QSCALE);
        } else if (c < 512) {
            int cc = c - 256, h = cc & 7, d = cc >> 3;
            Kp[((size_t)h * N + i) * HD + d] = f2bf(val);
        } else if (c < 768) {
            int cc = c - 512, h = cc & 7, d = cc >> 3;
            VpT[((size_t)h * HD + d) * N + i] = f2bf(val);
        } else {
            int cc = c - 768;
            if (cc >= 8) sigG[(size_t)(cc - 8) * N + i] = 1.f / (1.f + __expf(-val));
        }
    }
}

// ---- pass 1: colS[j,h] += sum_i 2^(S2_ij); j-tile 64 resident, i-loop 32 ----
// grid (16, NH, 8): x*4+w = j-tile of 64 (4 K-frags), z = i-chunk of 512
__global__ __launch_bounds__(256) void k_pass1(const unsigned short* __restrict__ Qp,
                                               const unsigned short* __restrict__ Kp,
                                               float* __restrict__ colS) {
    int w = threadIdx.x >> 6, l = threadIdx.x & 63;
    int il = l & 15, g = l >> 4;
    int h = blockIdx.y;
    int j0 = (blockIdx.x * 4 + w) * 64;
    const unsigned short* Kh = Kp + (size_t)h * N * HD;
    short8 Kf[4];
#pragma unroll
    for (int t = 0; t < 4; ++t)
        Kf[t] = *(const short8*)(Kh + (size_t)(j0 + 16 * t + il) * HD + g * 8);
    const unsigned short* Qh = Qp + (size_t)h * N * HD;
    f32x4 z = {0.f, 0.f, 0.f, 0.f};
    float s[4] = {0.f, 0.f, 0.f, 0.f};
    int ibeg = blockIdx.z * 512;
    short8 Qa = *(const short8*)(Qh + (size_t)(ibeg + il) * HD + g * 8);
    short8 Qb = *(const short8*)(Qh + (size_t)(ibeg + 16 + il) * HD + g * 8);
    for (int i0 = ibeg; i0 < ibeg + 512; i0 += 32) {
        short8 cQa = Qa, cQb = Qb;
        int in = i0 + 32;   // unconditional prefetch; last over-read lands in ws (safe)
        Qa = *(const short8*)(Qh + (size_t)(in + il) * HD + g * 8);
        Qb = *(const short8*)(Qh + (size_t)(in + 16 + il) * HD + g * 8);
#pragma unroll
        for (int t = 0; t < 4; ++t) {
            f32x4 Sa = __builtin_amdgcn_mfma_f32_16x16x32_bf16(cQa, Kf[t], z, 0, 0, 0);
            f32x4 Sb = __builtin_amdgcn_mfma_f32_16x16x32_bf16(cQb, Kf[t], z, 0, 0, 0);
            s[t] += ((__builtin_amdgcn_exp2f(Sa[0]) + __builtin_amdgcn_exp2f(Sa[1]))
                   + (__builtin_amdgcn_exp2f(Sa[2]) + __builtin_amdgcn_exp2f(Sa[3])))
                  + ((__builtin_amdgcn_exp2f(Sb[0]) + __builtin_amdgcn_exp2f(Sb[1]))
                   + (__builtin_amdgcn_exp2f(Sb[2]) + __builtin_amdgcn_exp2f(Sb[3])));
        }
    }
#pragma unroll
    for (int t = 0; t < 4; ++t) {
        s[t] += __shfl_xor(s[t], 16);
        s[t] += __shfl_xor(s[t], 32);
    }
    if (g == 0) {
#pragma unroll
        for (int t = 0; t < 4; ++t)
            atomicAdd(&colS[(size_t)h * N + j0 + 16 * t + il], s[t]);
    }
}

// ---- V-prescale (in place): V'[h][d][j] = V * sigG[h][j] / colS[h][j] ----
// grid (512): row = bx>>1 (0..255 = h*HD+d), half = bx&1; thread covers 8 j
__global__ void k_vprep(unsigned short* __restrict__ VpT,
                        const float* __restrict__ sigG,
                        const float* __restrict__ colS) {
    int row = blockIdx.x >> 1;
    int j0 = ((blockIdx.x & 1) * 256 + threadIdx.x) * 8;
    int h = row >> 5;
    unsigned short* p = VpT + (size_t)row * N + j0;
    short8 v = *(short8*)p;
    const float* sg = sigG + (size_t)h * N + j0;
    const float* cs = colS + (size_t)h * N + j0;
    f32x4 sa = *(const f32x4*)sg, sb = *(const f32x4*)(sg + 4);
    f32x4 ca = *(const f32x4*)cs, cb = *(const f32x4*)(cs + 4);
    unsigned o[4];
    o[0] = packbf2(bf2f((unsigned short)v[0]) * sa[0] / ca[0],
                   bf2f((unsigned short)v[1]) * sa[1] / ca[1]);
    o[1] = packbf2(bf2f((unsigned short)v[2]) * sa[2] / ca[2],
                   bf2f((unsigned short)v[3]) * sa[3] / ca[3]);
    o[2] = packbf2(bf2f((unsigned short)v[4]) * sb[0] / cb[0],
                   bf2f((unsigned short)v[5]) * sb[1] / cb[1]);
    o[3] = packbf2(bf2f((unsigned short)v[6]) * sb[2] / cb[2],
                   bf2f((unsigned short)v[7]) * sb[3] / cb[3]);
    uint4v ov; ov[0] = o[0]; ov[1] = o[1]; ov[2] = o[2]; ov[3] = o[3];
    *(uint4v*)p = ov;
}

// Assemble PV A-frag in registers from swapped-QK outputs.
// Inputs: Sa = scores for j-half0 (lane(il,g) holds j=4g+r, i=il),
//         Sb = j-half1. Output: lane(il,g) holds P[i=il][j=8g..8g+7] as short8.
static __device__ __forceinline__ short8 frag_dance(f32x4 Sa, f32x4 Sb) {
    unsigned A0 = packbf2(__builtin_amdgcn_exp2f(Sa[0]), __builtin_amdgcn_exp2f(Sa[1]));
    unsigned A1 = packbf2(__builtin_amdgcn_exp2f(Sa[2]), __builtin_amdgcn_exp2f(Sa[3]));
    unsigned B0 = packbf2(__builtin_amdgcn_exp2f(Sb[0]), __builtin_amdgcn_exp2f(Sb[1]));
    unsigned B1 = packbf2(__builtin_amdgcn_exp2f(Sb[2]), __builtin_amdgcn_exp2f(Sb[3]));
    uint2v r1 = __builtin_amdgcn_permlane32_swap(A0, B0, false, false);
    uint2v r2 = __builtin_amdgcn_permlane16_swap(r1[0], r1[1], false, false); // dw0, dw2
    uint2v r3 = __builtin_amdgcn_permlane32_swap(A1, B1, false, false);
    uint2v r4 = __builtin_amdgcn_permlane16_swap(r3[0], r3[1], false, false); // dw1, dw3
    uint4v pu;
    pu[0] = r2[0]; pu[1] = r4[0]; pu[2] = r2[1]; pu[3] = r4[1];
    return __builtin_bit_cast(short8, pu);
}

// ---- pass 2: Vpart[z][h][i][d] = sum_{j in chunk} 2^(S2_ij) * V'[j,d] ----
// grid (16, NH, CH): x*4+w = i-tile of 64 rows (4 Q-frags), z = j-chunk of 512.
// 1-deep K/V software pipeline, unconditional prefetch.
__global__ __launch_bounds__(256) void k_pass2(const unsigned short* __restrict__ Qp,
                                               const unsigned short* __restrict__ Kp,
                                               const unsigned short* __restrict__ VpT,
                                               float* __restrict__ Vpart) {
    int w = threadIdx.x >> 6, l = threadIdx.x & 63;
    int il = l & 15, g = l >> 4;
    int h = blockIdx.y;
    int i0 = (blockIdx.x * 4 + w) * 64;
    int jbeg = blockIdx.z * JSPAN;
    const unsigned short* Qh = Qp + (size_t)h * N * HD;
    const unsigned short* Kh = Kp + ((size_t)h * N + jbeg) * HD;
    const unsigned short* Vh = VpT + (size_t)h * HD * N + jbeg;
    short8 Qf[4];
#pragma unroll
    for (int q = 0; q < 4; ++q)
        Qf[q] = *(const short8*)(Qh + (size_t)(i0 + q * 16 + il) * HD + g * 8);
    f32x4 z = {0.f, 0.f, 0.f, 0.f};
    f32x4 acc[4][2];
#pragma unroll
    for (int q = 0; q < 4; ++q) {
        acc[q][0] = z;
        acc[q][1] = z;
    }
    // prologue: load jb = 0 operands
    short8 K0 = *(const short8*)(Kh + (size_t)il * HD + g * 8);
    short8 K1 = *(const short8*)(Kh + (size_t)(16 + il) * HD + g * 8);
    short8 V0 = *(const short8*)(Vh + (size_t)il * N + g * 8);
    short8 V1 = *(const short8*)(Vh + (size_t)(16 + il) * N + g * 8);
    for (int jb = 0; jb < JSPAN; jb += 32) {
        short8 cK0 = K0, cK1 = K1, cV0 = V0, cV1 = V1;
        int jn = jb + 32;   // unconditional prefetch; last over-read lands in ws (safe)
        K0 = *(const short8*)(Kh + (size_t)(jn + il) * HD + g * 8);
        K1 = *(const short8*)(Kh + (size_t)(jn + 16 + il) * HD + g * 8);
        V0 = *(const short8*)(Vh + (size_t)il * N + jn + g * 8);
        V1 = *(const short8*)(Vh + (size_t)(16 + il) * N + jn + g * 8);
#pragma unroll
        for (int q = 0; q < 4; ++q) {
            // swapped QK: lane(il,g) gets S[j=4g+r][i=il]
            f32x4 SA = __builtin_amdgcn_mfma_f32_16x16x32_bf16(cK0, Qf[q], z, 0, 0, 0);
            f32x4 SB = __builtin_amdgcn_mfma_f32_16x16x32_bf16(cK1, Qf[q], z, 0, 0, 0);
            short8 Pa = frag_dance(SA, SB);
            acc[q][0] = __builtin_amdgcn_mfma_f32_16x16x32_bf16(Pa, cV0, acc[q][0], 0, 0, 0);
            acc[q][1] = __builtin_amdgcn_mfma_f32_16x16x32_bf16(Pa, cV1, acc[q][1], 0, 0, 0);
        }
    }
    float* Vout = Vpart + (size_t)(blockIdx.z * NH + h) * N * HD;
#pragma unroll
    for (int q = 0; q < 4; ++q) {
#pragma unroll
        for (int r = 0; r < 4; ++r) {
            int ia = i0 + q * 16 + g * 4 + r;
            Vout[(size_t)ia * HD + il]      = acc[q][0][r];   // coalesced 64B/quarter-wave
            Vout[(size_t)ia * HD + 16 + il] = acc[q][1][r];
        }
    }
}

// ---- layernorm: sum CH partials (layout [ch][h][i][d]), normalize, scatter ----
__global__ __launch_bounds__(256) void k_ln(const float* __restrict__ Vpart,
                                            const float* __restrict__ gam,
                                            const float* __restrict__ bet,
                                            float* __restrict__ out) {
    int w = threadIdx.x >> 6, l = threadIdx.x & 63;
    int i = blockIdx.x * 4 + w;
    int h = l >> 3, d0 = (l & 7) << 2;   // lane owns channels c = (d0+r)*8 + h
    f32x4 x = {0.f, 0.f, 0.f, 0.f};
#pragma unroll
    for (int c = 0; c < CH; ++c) {
        f32x4 v = *(const f32x4*)(Vpart + ((size_t)(c * NH + h) * N + i) * HD + d0);
        x[0] += v[0]; x[1] += v[1]; x[2] += v[2]; x[3] += v[3];
    }
    float s1 = x[0] + x[1] + x[2] + x[3];
    float s2 = x[0] * x[0] + x[1] * x[1] + x[2] * x[2] + x[3] * x[3];
#pragma unroll
    for (int off = 1; off < 64; off <<= 1) {
        s1 += __shfl_xor(s1, off);
        s2 += __shfl_xor(s2, off);
    }
    float mu = s1 * (1.f / 256.f);
    float var = s2 * (1.f / 256.f) - mu * mu;
    float rs = rsqrtf(var + 1e-3f);
#pragma unroll
    for (int r = 0; r < 4; ++r) {
        int c = (d0 + r) * 8 + h;
        out[(size_t)i * HID + c] = (x[r] - mu) * rs * gam[c] + bet[c];
    }
}

extern "C" void kernel_launch(void* const* d_in, const int* in_sizes, int n_in,
                              void* d_out, int out_size, void* d_ws, size_t ws_size,
                              hipStream_t stream) {
    const float* feat = (const float*)d_in[0];
    const float* Wq   = (const float*)d_in[1];
    const float* bq   = (const float*)d_in[2];
    const float* Wkv  = (const float*)d_in[3];
    const float* bkv  = (const float*)d_in[4];
    const float* Weg  = (const float*)d_in[5];
    const float* beg  = (const float*)d_in[6];
    const float* ln_g = (const float*)d_in[7];
    const float* ln_b = (const float*)d_in[8];
    float* out = (float*)d_out;

    char* ws = (char*)d_ws;
    unsigned short* Qp    = (unsigned short*)(ws + 0);                     // 2 MB
    unsigned short* Kp    = (unsigned short*)(ws + (2u << 20));            // 2 MB
    unsigned short* VpT   = (unsigned short*)(ws + (4u << 20));            // 2 MB
    unsigned short* featb = (unsigned short*)(ws + (6u << 20));            // 2 MB
    unsigned short* WbT   = (unsigned short*)(ws + (8u << 20));            // 0.4 MB
    float* bC   = (float*)(ws + (8u << 20) + (512u << 10));                // 3 KB
    float* sigG = (float*)(ws + (8u << 20) + (528u << 10));                // 128 KB
    float* colS = (float*)(ws + (8u << 20) + (656u << 10));                // 128 KB
    float* Vpart = (float*)(ws + (9u << 20));                              // CH*4 MB

    k_prep<<<dim3(1024 + NC), 256, 0, stream>>>(feat, Wq, Wkv, Weg, bq, bkv, beg,
                                                featb, WbT, bC, colS);
    k_proj<<<dim3(49, 64), 256, 0, stream>>>(featb, WbT, bC, Qp, Kp, VpT, sigG);
    k_pass1<<<dim3(16, NH, 8), 256, 0, stream>>>(Qp, Kp, colS);
    k_vprep<<<dim3(512), 256, 0, stream>>>(VpT, sigG, colS);
    k_pass2<<<dim3(16, NH, CH), 256, 0, stream>>>(Qp, Kp, VpT, Vpart);
    k_ln<<<dim3(1024), 256, 0, stream>>>(Vpart, ln_g, ln_b, out);
}

// Round 8
// 107.445 us; speedup vs baseline: 1.0366x; 1.0366x over previous
//
#include <hip/hip_runtime.h>
#include <hip/hip_bf16.h>

#define N 4096
#define HID 256
#define NH 8
#define HD 32
#define NC 784    // 256 Q | 256 K | 256 V | 16 EG
#define CH 8      // j-chunks (ws >= 41 MB proven)
#define JSPAN (N / CH)

typedef __attribute__((ext_vector_type(8))) short short8;
typedef __attribute__((ext_vector_type(4))) short short4v;
typedef __attribute__((ext_vector_type(4))) float f32x4;
typedef __attribute__((ext_vector_type(2))) unsigned int uint2v;
typedef __attribute__((ext_vector_type(4))) unsigned int uint4v;

// Q scale = (1/sqrt(32)) * log2(e): folds softmax temp AND exp->exp2 conversion
#define QSCALE 0.25503482f

static __device__ __forceinline__ unsigned short f2bf(float f) {
    union { float f; unsigned u; } v; v.f = f;
    unsigned r = v.u + 0x7fff + ((v.u >> 16) & 1);
    return (unsigned short)(r >> 16);
}
static __device__ __forceinline__ float bf2f(unsigned short u) {
    union { unsigned u; float f; } v; v.u = ((unsigned)u) << 16; return v.f;
}
static __device__ __forceinline__ unsigned packbf2(float a, float b) {
    __hip_bfloat162 t = __float22bfloat162_rn(make_float2(a, b));
    unsigned u; __builtin_memcpy(&u, &t, 4); return u;
}

// ---- fused prep: feat->bf16 (blocks 0..1023) | WbT/bC build + colS zero ----
__global__ void k_prep(const float* __restrict__ feat, const float* __restrict__ Wq,
                       const float* __restrict__ Wkv, const float* __restrict__ Weg,
                       const float* __restrict__ bq, const float* __restrict__ bkv,
                       const float* __restrict__ beg, unsigned short* __restrict__ featb,
                       unsigned short* __restrict__ WbT, float* __restrict__ bC,
                       float* __restrict__ colS) {
    int bx = blockIdx.x;
    if (bx < 1024) {
        int t = bx * 256 + threadIdx.x;
        float4 v = ((const float4*)feat)[t];
        short4v o;
        o[0] = (short)f2bf(v.x); o[1] = (short)f2bf(v.y);
        o[2] = (short)f2bf(v.z); o[3] = (short)f2bf(v.w);
        ((short4v*)featb)[t] = o;
    } else {
        int c = bx - 1024, k = threadIdx.x;
        float w, b;
        if (c < 256)      { w = Wq[k * 256 + c];          b = bq[c]; }
        else if (c < 768) { w = Wkv[k * 512 + (c - 256)]; b = bkv[c - 256]; }
        else              { w = Weg[k * 16 + (c - 768)];  b = beg[c - 768]; }
        WbT[c * 256 + k] = f2bf(w);
        if (k == 0) bC[c] = b;
        if (c < 128) colS[c * 256 + k] = 0.f;
    }
}

// ---- projection GEMM: [4096,256]x[256,784]; scatter into packed layouts ----
__global__ __launch_bounds__(256) void k_proj(const unsigned short* __restrict__ featb,
                                              const unsigned short* __restrict__ WbT,
                                              const float* __restrict__ bC,
                                              unsigned short* __restrict__ Qp,
                                              unsigned short* __restrict__ Kp,
                                              unsigned short* __restrict__ VpT,
                                              float* __restrict__ sigG) {
    int w = threadIdx.x >> 6, l = threadIdx.x & 63;
    int il = l & 15, g = l >> 4;
    int c0 = blockIdx.x * 16;
    int i0 = (blockIdx.y * 4 + w) * 16;
    const short8* Arow = (const short8*)(featb + (size_t)(i0 + il) * HID);
    const short8* Brow = (const short8*)(WbT + (size_t)(c0 + il) * HID);
    f32x4 acc = {0.f, 0.f, 0.f, 0.f};
#pragma unroll
    for (int k0 = 0; k0 < HID; k0 += 32) {
        short8 a = Arow[(k0 >> 3) + g];
        short8 b = Brow[(k0 >> 3) + g];
        acc = __builtin_amdgcn_mfma_f32_16x16x32_bf16(a, b, acc, 0, 0, 0);
    }
    int c = c0 + il;
    float bias = bC[c];
#pragma unroll
    for (int r = 0; r < 4; ++r) {
        int i = i0 + g * 4 + r;
        float val = acc[r] + bias;
        if (c < 256) {
            int h = c & 7, d = c >> 3;
            Qp[((size_t)h * N + i) * HD + d] = f2bf(val * QSCALE);
        } else if (c < 512) {
            int cc = c - 256, h = cc & 7, d = cc >> 3;
            Kp[((size_t)h * N + i) * HD + d] = f2bf(val);
        } else if (c < 768) {
            int cc = c - 512, h = cc & 7, d = cc >> 3;
            VpT[((size_t)h * HD + d) * N + i] = f2bf(val);
        } else {
            int cc = c - 768;
            if (cc >= 8) sigG[(size_t)(cc - 8) * N + i] = 1.f / (1.f + __expf(-val));
        }
    }
}

// ---- pass 1: colS[j,h] += sum_i 2^(S2_ij); j-tile 64 resident, i-chunk 256 ----
// grid (16, NH, 16): x*4+w = j-tile of 64 (4 K-frags), z = i-chunk of 256
__global__ __launch_bounds__(256) void k_pass1(const unsigned short* __restrict__ Qp,
                                               const unsigned short* __restrict__ Kp,
                                               float* __restrict__ colS) {
    int w = threadIdx.x >> 6, l = threadIdx.x & 63;
    int il = l & 15, g = l >> 4;
    int h = blockIdx.y;
    int j0 = (blockIdx.x * 4 + w) * 64;
    const unsigned short* Kh = Kp + (size_t)h * N * HD;
    short8 Kf[4];
#pragma unroll
    for (int t = 0; t < 4; ++t)
        Kf[t] = *(const short8*)(Kh + (size_t)(j0 + 16 * t + il) * HD + g * 8);
    const unsigned short* Qh = Qp + (size_t)h * N * HD;
    f32x4 z = {0.f, 0.f, 0.f, 0.f};
    float s[4] = {0.f, 0.f, 0.f, 0.f};
    int ibeg = blockIdx.z * 256;
    short8 Qa = *(const short8*)(Qh + (size_t)(ibeg + il) * HD + g * 8);
    short8 Qb = *(const short8*)(Qh + (size_t)(ibeg + 16 + il) * HD + g * 8);
    for (int i0 = ibeg; i0 < ibeg + 256; i0 += 32) {
        short8 cQa = Qa, cQb = Qb;
        int in = i0 + 32;   // unconditional prefetch; last over-read lands in ws (safe)
        Qa = *(const short8*)(Qh + (size_t)(in + il) * HD + g * 8);
        Qb = *(const short8*)(Qh + (size_t)(in + 16 + il) * HD + g * 8);
#pragma unroll
        for (int t = 0; t < 4; ++t) {
            f32x4 Sa = __builtin_amdgcn_mfma_f32_16x16x32_bf16(cQa, Kf[t], z, 0, 0, 0);
            f32x4 Sb = __builtin_amdgcn_mfma_f32_16x16x32_bf16(cQb, Kf[t], z, 0, 0, 0);
            s[t] += ((__builtin_amdgcn_exp2f(Sa[0]) + __builtin_amdgcn_exp2f(Sa[1]))
                   + (__builtin_amdgcn_exp2f(Sa[2]) + __builtin_amdgcn_exp2f(Sa[3])))
                  + ((__builtin_amdgcn_exp2f(Sb[0]) + __builtin_amdgcn_exp2f(Sb[1]))
                   + (__builtin_amdgcn_exp2f(Sb[2]) + __builtin_amdgcn_exp2f(Sb[3])));
        }
    }
#pragma unroll
    for (int t = 0; t < 4; ++t) {
        s[t] += __shfl_xor(s[t], 16);
        s[t] += __shfl_xor(s[t], 32);
    }
    if (g == 0) {
#pragma unroll
        for (int t = 0; t < 4; ++t)
            atomicAdd(&colS[(size_t)h * N + j0 + 16 * t + il], s[t]);
    }
}

// ---- V-prescale (in place): V'[h][d][j] = V * sigG[h][j] / colS[h][j] ----
__global__ void k_vprep(unsigned short* __restrict__ VpT,
                        const float* __restrict__ sigG,
                        const float* __restrict__ colS) {
    int row = blockIdx.x >> 1;
    int j0 = ((blockIdx.x & 1) * 256 + threadIdx.x) * 8;
    int h = row >> 5;
    unsigned short* p = VpT + (size_t)row * N + j0;
    short8 v = *(short8*)p;
    const float* sg = sigG + (size_t)h * N + j0;
    const float* cs = colS + (size_t)h * N + j0;
    f32x4 sa = *(const f32x4*)sg, sb = *(const f32x4*)(sg + 4);
    f32x4 ca = *(const f32x4*)cs, cb = *(const f32x4*)(cs + 4);
    unsigned o[4];
    o[0] = packbf2(bf2f((unsigned short)v[0]) * sa[0] / ca[0],
                   bf2f((unsigned short)v[1]) * sa[1] / ca[1]);
    o[1] = packbf2(bf2f((unsigned short)v[2]) * sa[2] / ca[2],
                   bf2f((unsigned short)v[3]) * sa[3] / ca[3]);
    o[2] = packbf2(bf2f((unsigned short)v[4]) * sb[0] / cb[0],
                   bf2f((unsigned short)v[5]) * sb[1] / cb[1]);
    o[3] = packbf2(bf2f((unsigned short)v[6]) * sb[2] / cb[2],
                   bf2f((unsigned short)v[7]) * sb[3] / cb[3]);
    uint4v ov; ov[0] = o[0]; ov[1] = o[1]; ov[2] = o[2]; ov[3] = o[3];
    *(uint4v*)p = ov;
}

// Assemble PV A-frag in registers from swapped-QK outputs.
static __device__ __forceinline__ short8 frag_dance(f32x4 Sa, f32x4 Sb) {
    unsigned A0 = packbf2(__builtin_amdgcn_exp2f(Sa[0]), __builtin_amdgcn_exp2f(Sa[1]));
    unsigned A1 = packbf2(__builtin_amdgcn_exp2f(Sa[2]), __builtin_amdgcn_exp2f(Sa[3]));
    unsigned B0 = packbf2(__builtin_amdgcn_exp2f(Sb[0]), __builtin_amdgcn_exp2f(Sb[1]));
    unsigned B1 = packbf2(__builtin_amdgcn_exp2f(Sb[2]), __builtin_amdgcn_exp2f(Sb[3]));
    uint2v r1 = __builtin_amdgcn_permlane32_swap(A0, B0, false, false);
    uint2v r2 = __builtin_amdgcn_permlane16_swap(r1[0], r1[1], false, false); // dw0, dw2
    uint2v r3 = __builtin_amdgcn_permlane32_swap(A1, B1, false, false);
    uint2v r4 = __builtin_amdgcn_permlane16_swap(r3[0], r3[1], false, false); // dw1, dw3
    uint4v pu;
    pu[0] = r2[0]; pu[1] = r4[0]; pu[2] = r2[1]; pu[3] = r4[1];
    return __builtin_bit_cast(short8, pu);
}

// ---- pass 2: Vpart[z][h][i][d] (bf16) = sum_{j in chunk} 2^(S2_ij) * V'[j,d] ----
// grid (64, NH, CH), 128-thr blocks: block = i-tile 64 (4 Q-frags/wave);
// wave w covers j in [w*256, w*256+256) of the chunk; LDS-combined epilogue.
__global__ __launch_bounds__(128) void k_pass2(const unsigned short* __restrict__ Qp,
                                               const unsigned short* __restrict__ Kp,
                                               const unsigned short* __restrict__ VpT,
                                               unsigned short* __restrict__ Vpb) {
    __shared__ __align__(16) float comb[64 * 36];   // stride 36 floats: 16B-aligned, conflict-free
    int w = threadIdx.x >> 6, l = threadIdx.x & 63;
    int il = l & 15, g = l >> 4;
    int h = blockIdx.y;
    int i0 = blockIdx.x * 64;
    int jbeg = blockIdx.z * JSPAN + w * (JSPAN / 2);
    const unsigned short* Qh = Qp + (size_t)h * N * HD;
    const unsigned short* Kh = Kp + ((size_t)h * N + jbeg) * HD;
    const unsigned short* Vh = VpT + (size_t)h * HD * N + jbeg;
    short8 Qf[4];
#pragma unroll
    for (int q = 0; q < 4; ++q)
        Qf[q] = *(const short8*)(Qh + (size_t)(i0 + q * 16 + il) * HD + g * 8);
    f32x4 z = {0.f, 0.f, 0.f, 0.f};
    f32x4 acc[4][2];
#pragma unroll
    for (int q = 0; q < 4; ++q) { acc[q][0] = z; acc[q][1] = z; }
    // prologue: load jb = 0 operands
    short8 K0 = *(const short8*)(Kh + (size_t)il * HD + g * 8);
    short8 K1 = *(const short8*)(Kh + (size_t)(16 + il) * HD + g * 8);
    short8 V0 = *(const short8*)(Vh + (size_t)il * N + g * 8);
    short8 V1 = *(const short8*)(Vh + (size_t)(16 + il) * N + g * 8);
    for (int jb = 0; jb < JSPAN / 2; jb += 32) {
        short8 cK0 = K0, cK1 = K1, cV0 = V0, cV1 = V1;
        int jn = jb + 32;   // unconditional prefetch; over-read lands in ws (safe)
        K0 = *(const short8*)(Kh + (size_t)(jn + il) * HD + g * 8);
        K1 = *(const short8*)(Kh + (size_t)(jn + 16 + il) * HD + g * 8);
        V0 = *(const short8*)(Vh + (size_t)il * N + jn + g * 8);
        V1 = *(const short8*)(Vh + (size_t)(16 + il) * N + jn + g * 8);
#pragma unroll
        for (int q = 0; q < 4; ++q) {
            // swapped QK: lane(il,g) gets S[j=4g+r][i=il]
            f32x4 SA = __builtin_amdgcn_mfma_f32_16x16x32_bf16(cK0, Qf[q], z, 0, 0, 0);
            f32x4 SB = __builtin_amdgcn_mfma_f32_16x16x32_bf16(cK1, Qf[q], z, 0, 0, 0);
            short8 Pa = frag_dance(SA, SB);
            acc[q][0] = __builtin_amdgcn_mfma_f32_16x16x32_bf16(Pa, cV0, acc[q][0], 0, 0, 0);
            acc[q][1] = __builtin_amdgcn_mfma_f32_16x16x32_bf16(Pa, cV1, acc[q][1], 0, 0, 0);
        }
    }
    // combine the two waves' partials, store bf16
    if (w == 1) {
#pragma unroll
        for (int q = 0; q < 4; ++q) {
            *(f32x4*)(comb + l * 36 + q * 8)     = acc[q][0];
            *(f32x4*)(comb + l * 36 + q * 8 + 4) = acc[q][1];
        }
    }
    __syncthreads();
    if (w == 0) {
        unsigned short* Vout = Vpb + (size_t)(blockIdx.z * NH + h) * N * HD;
#pragma unroll
        for (int q = 0; q < 4; ++q) {
            f32x4 o0 = *(const f32x4*)(comb + l * 36 + q * 8);
            f32x4 o1 = *(const f32x4*)(comb + l * 36 + q * 8 + 4);
#pragma unroll
            for (int r = 0; r < 4; ++r) {
                int ia = i0 + q * 16 + g * 4 + r;
                Vout[(size_t)ia * HD + il]      = f2bf(acc[q][0][r] + o0[r]);
                Vout[(size_t)ia * HD + 16 + il] = f2bf(acc[q][1][r] + o1[r]);
            }
        }
    }
}

// ---- layernorm: sum CH bf16 partials (layout [ch][h][i][d]), normalize ----
__global__ __launch_bounds__(256) void k_ln(const unsigned short* __restrict__ Vpb,
                                            const float* __restrict__ gam,
                                            const float* __restrict__ bet,
                                            float* __restrict__ out) {
    int w = threadIdx.x >> 6, l = threadIdx.x & 63;
    int i = blockIdx.x * 4 + w;
    int h = l >> 3, d0 = (l & 7) << 2;   // lane owns channels c = (d0+r)*8 + h
    f32x4 x = {0.f, 0.f, 0.f, 0.f};
#pragma unroll
    for (int c = 0; c < CH; ++c) {
        short4v v = *(const short4v*)(Vpb + ((size_t)(c * NH + h) * N + i) * HD + d0);
        x[0] += bf2f((unsigned short)v[0]); x[1] += bf2f((unsigned short)v[1]);
        x[2] += bf2f((unsigned short)v[2]); x[3] += bf2f((unsigned short)v[3]);
    }
    float s1 = x[0] + x[1] + x[2] + x[3];
    float s2 = x[0] * x[0] + x[1] * x[1] + x[2] * x[2] + x[3] * x[3];
#pragma unroll
    for (int off = 1; off < 64; off <<= 1) {
        s1 += __shfl_xor(s1, off);
        s2 += __shfl_xor(s2, off);
    }
    float mu = s1 * (1.f / 256.f);
    float var = s2 * (1.f / 256.f) - mu * mu;
    float rs = rsqrtf(var + 1e-3f);
#pragma unroll
    for (int r = 0; r < 4; ++r) {
        int c = (d0 + r) * 8 + h;
        out[(size_t)i * HID + c] = (x[r] - mu) * rs * gam[c] + bet[c];
    }
}

extern "C" void kernel_launch(void* const* d_in, const int* in_sizes, int n_in,
                              void* d_out, int out_size, void* d_ws, size_t ws_size,
                              hipStream_t stream) {
    const float* feat = (const float*)d_in[0];
    const float* Wq   = (const float*)d_in[1];
    const float* bq   = (const float*)d_in[2];
    const float* Wkv  = (const float*)d_in[3];
    const float* bkv  = (const float*)d_in[4];
    const float* Weg  = (const float*)d_in[5];
    const float* beg  = (const float*)d_in[6];
    const float* ln_g = (const float*)d_in[7];
    const float* ln_b = (const float*)d_in[8];
    float* out = (float*)d_out;

    char* ws = (char*)d_ws;
    unsigned short* Qp    = (unsigned short*)(ws + 0);                     // 2 MB
    unsigned short* Kp    = (unsigned short*)(ws + (2u << 20));            // 2 MB
    unsigned short* VpT   = (unsigned short*)(ws + (4u << 20));            // 2 MB
    unsigned short* featb = (unsigned short*)(ws + (6u << 20));            // 2 MB
    unsigned short* WbT   = (unsigned short*)(ws + (8u << 20));            // 0.4 MB
    float* bC   = (float*)(ws + (8u << 20) + (512u << 10));                // 3 KB
    float* sigG = (float*)(ws + (8u << 20) + (528u << 10));                // 128 KB
    float* colS = (float*)(ws + (8u << 20) + (656u << 10));                // 128 KB
    unsigned short* Vpb = (unsigned short*)(ws + (9u << 20));              // CH*2 MB bf16

    k_prep<<<dim3(1024 + NC), 256, 0, stream>>>(feat, Wq, Wkv, Weg, bq, bkv, beg,
                                                featb, WbT, bC, colS);
    k_proj<<<dim3(49, 64), 256, 0, stream>>>(featb, WbT, bC, Qp, Kp, VpT, sigG);
    k_pass1<<<dim3(16, NH, 16), 256, 0, stream>>>(Qp, Kp, colS);
    k_vprep<<<dim3(512), 256, 0, stream>>>(VpT, sigG, colS);
    k_pass2<<<dim3(64, NH, CH), 128, 0, stream>>>(Qp, Kp, VpT, Vpb);
    k_ln<<<dim3(1024), 256, 0, stream>>>(Vpb, ln_g, ln_b, out);
}

// Round 10
// 104.115 us; speedup vs baseline: 1.0697x; 1.0320x over previous
//
#include <hip/hip_runtime.h>
#include <hip/hip_bf16.h>

#define N 4096
#define HID 256
#define NH 8
#define HD 32
#define NC 784    // 256 Q | 256 K | 256 V | 16 EG
#define CH 8      // j-chunks (ws >= 41 MB proven)
#define JSPAN (N / CH)

typedef __attribute__((ext_vector_type(8))) short short8;
typedef __attribute__((ext_vector_type(4))) short short4v;
typedef __attribute__((ext_vector_type(4))) float f32x4;
typedef __attribute__((ext_vector_type(2))) unsigned int uint2v;
typedef __attribute__((ext_vector_type(4))) unsigned int uint4v;

// Q scale = (1/sqrt(32)) * log2(e): folds softmax temp AND exp->exp2 conversion
#define QSCALE 0.25503482f

static __device__ __forceinline__ unsigned short f2bf(float f) {
    union { float f; unsigned u; } v; v.f = f;
    unsigned r = v.u + 0x7fff + ((v.u >> 16) & 1);
    return (unsigned short)(r >> 16);
}
static __device__ __forceinline__ float bf2f(unsigned short u) {
    union { unsigned u; float f; } v; v.u = ((unsigned)u) << 16; return v.f;
}
// branchless RNE pack: dst.lo = bf16(a), dst.hi = bf16(b).  ~6 VALU:
// 2x(v_bfe+v_add3) + v_lshrrev + v_and_or_b32. No NaN path (inputs finite).
static __device__ __forceinline__ unsigned packrnd(float a, float b) {
    unsigned ua = __builtin_bit_cast(unsigned, a);
    unsigned ub = __builtin_bit_cast(unsigned, b);
    ua = ua + 0x7fffu + ((ua >> 16) & 1u);
    ub = ub + 0x7fffu + ((ub >> 16) & 1u);
    return (ua >> 16) | (ub & 0xffff0000u);
}

// ---- fused prep: feat->bf16 (blocks 0..1023) | WbT/bC build + colS zero ----
__global__ void k_prep(const float* __restrict__ feat, const float* __restrict__ Wq,
                       const float* __restrict__ Wkv, const float* __restrict__ Weg,
                       const float* __restrict__ bq, const float* __restrict__ bkv,
                       const float* __restrict__ beg, unsigned short* __restrict__ featb,
                       unsigned short* __restrict__ WbT, float* __restrict__ bC,
                       float* __restrict__ colS) {
    int bx = blockIdx.x;
    if (bx < 1024) {
        int t = bx * 256 + threadIdx.x;
        float4 v = ((const float4*)feat)[t];
        short4v o;
        o[0] = (short)f2bf(v.x); o[1] = (short)f2bf(v.y);
        o[2] = (short)f2bf(v.z); o[3] = (short)f2bf(v.w);
        ((short4v*)featb)[t] = o;
    } else {
        int c = bx - 1024, k = threadIdx.x;
        float w, b;
        if (c < 256)      { w = Wq[k * 256 + c];          b = bq[c]; }
        else if (c < 768) { w = Wkv[k * 512 + (c - 256)]; b = bkv[c - 256]; }
        else              { w = Weg[k * 16 + (c - 768)];  b = beg[c - 768]; }
        WbT[c * 256 + k] = f2bf(w);
        if (k == 0) bC[c] = b;
        if (c < 128) colS[c * 256 + k] = 0.f;
    }
}

// ---- projection GEMM: [4096,256]x[256,784]; scatter into packed layouts ----
__global__ __launch_bounds__(256) void k_proj(const unsigned short* __restrict__ featb,
                                              const unsigned short* __restrict__ WbT,
                                              const float* __restrict__ bC,
                                              unsigned short* __restrict__ Qp,
                                              unsigned short* __restrict__ Kp,
                                              unsigned short* __restrict__ VpT,
                                              float* __restrict__ sigG) {
    int w = threadIdx.x >> 6, l = threadIdx.x & 63;
    int il = l & 15, g = l >> 4;
    int c0 = blockIdx.x * 16;
    int i0 = (blockIdx.y * 4 + w) * 16;
    const short8* Arow = (const short8*)(featb + (size_t)(i0 + il) * HID);
    const short8* Brow = (const short8*)(WbT + (size_t)(c0 + il) * HID);
    f32x4 acc = {0.f, 0.f, 0.f, 0.f};
#pragma unroll
    for (int k0 = 0; k0 < HID; k0 += 32) {
        short8 a = Arow[(k0 >> 3) + g];
        short8 b = Brow[(k0 >> 3) + g];
        acc = __builtin_amdgcn_mfma_f32_16x16x32_bf16(a, b, acc, 0, 0, 0);
    }
    int c = c0 + il;
    float bias = bC[c];
#pragma unroll
    for (int r = 0; r < 4; ++r) {
        int i = i0 + g * 4 + r;
        float val = acc[r] + bias;
        if (c < 256) {
            int h = c & 7, d = c >> 3;
            Qp[((size_t)h * N + i) * HD + d] = f2bf(val * QSCALE);
        } else if (c < 512) {
            int cc = c - 256, h = cc & 7, d = cc >> 3;
            Kp[((size_t)h * N + i) * HD + d] = f2bf(val);
        } else if (c < 768) {
            int cc = c - 512, h = cc & 7, d = cc >> 3;
            VpT[((size_t)h * HD + d) * N + i] = f2bf(val);
        } else {
            int cc = c - 768;
            if (cc >= 8) sigG[(size_t)(cc - 8) * N + i] = 1.f / (1.f + __expf(-val));
        }
    }
}

// ---- pass 1: colS[j,h] += sum_i 2^(S2_ij); j-tile 64 resident, i-chunk 256 ----
// grid (16, NH, 16): x*4+w = j-tile of 64 (4 K-frags), z = i-chunk of 256
__global__ __launch_bounds__(256) void k_pass1(const unsigned short* __restrict__ Qp,
                                               const unsigned short* __restrict__ Kp,
                                               float* __restrict__ colS) {
    int w = threadIdx.x >> 6, l = threadIdx.x & 63;
    int il = l & 15, g = l >> 4;
    int h = blockIdx.y;
    int j0 = (blockIdx.x * 4 + w) * 64;
    const unsigned short* Kh = Kp + (size_t)h * N * HD;
    short8 Kf[4];
#pragma unroll
    for (int t = 0; t < 4; ++t)
        Kf[t] = *(const short8*)(Kh + (size_t)(j0 + 16 * t + il) * HD + g * 8);
    const unsigned short* Qh = Qp + (size_t)h * N * HD;
    f32x4 z = {0.f, 0.f, 0.f, 0.f};
    float s[4] = {0.f, 0.f, 0.f, 0.f};
    int ibeg = blockIdx.z * 256;
    short8 Qa = *(const short8*)(Qh + (size_t)(ibeg + il) * HD + g * 8);
    short8 Qb = *(const short8*)(Qh + (size_t)(ibeg + 16 + il) * HD + g * 8);
#pragma unroll
    for (int it = 0; it < 8; ++it) {
        int i0 = ibeg + it * 32;
        short8 cQa = Qa, cQb = Qb;
        int in = i0 + 32;   // unconditional prefetch; last over-read lands in ws (safe)
        Qa = *(const short8*)(Qh + (size_t)(in + il) * HD + g * 8);
        Qb = *(const short8*)(Qh + (size_t)(in + 16 + il) * HD + g * 8);
#pragma unroll
        for (int t = 0; t < 4; ++t) {
            f32x4 Sa = __builtin_amdgcn_mfma_f32_16x16x32_bf16(cQa, Kf[t], z, 0, 0, 0);
            f32x4 Sb = __builtin_amdgcn_mfma_f32_16x16x32_bf16(cQb, Kf[t], z, 0, 0, 0);
            s[t] += ((__builtin_amdgcn_exp2f(Sa[0]) + __builtin_amdgcn_exp2f(Sa[1]))
                   + (__builtin_amdgcn_exp2f(Sa[2]) + __builtin_amdgcn_exp2f(Sa[3])))
                  + ((__builtin_amdgcn_exp2f(Sb[0]) + __builtin_amdgcn_exp2f(Sb[1]))
                   + (__builtin_amdgcn_exp2f(Sb[2]) + __builtin_amdgcn_exp2f(Sb[3])));
        }
    }
#pragma unroll
    for (int t = 0; t < 4; ++t) {
        s[t] += __shfl_xor(s[t], 16);
        s[t] += __shfl_xor(s[t], 32);
    }
    if (g == 0) {
#pragma unroll
        for (int t = 0; t < 4; ++t)
            atomicAdd(&colS[(size_t)h * N + j0 + 16 * t + il], s[t]);
    }
}

// ---- V-prescale (in place): V'[h][d][j] = V * sigG[h][j] / colS[h][j] ----
__global__ void k_vprep(unsigned short* __restrict__ VpT,
                        const float* __restrict__ sigG,
                        const float* __restrict__ colS) {
    int row = blockIdx.x >> 1;
    int j0 = ((blockIdx.x & 1) * 256 + threadIdx.x) * 8;
    int h = row >> 5;
    unsigned short* p = VpT + (size_t)row * N + j0;
    short8 v = *(short8*)p;
    const float* sg = sigG + (size_t)h * N + j0;
    const float* cs = colS + (size_t)h * N + j0;
    f32x4 sa = *(const f32x4*)sg, sb = *(const f32x4*)(sg + 4);
    f32x4 ca = *(const f32x4*)cs, cb = *(const f32x4*)(cs + 4);
    uint4v ov;
    ov[0] = packrnd(bf2f((unsigned short)v[0]) * sa[0] / ca[0],
                    bf2f((unsigned short)v[1]) * sa[1] / ca[1]);
    ov[1] = packrnd(bf2f((unsigned short)v[2]) * sa[2] / ca[2],
                    bf2f((unsigned short)v[3]) * sa[3] / ca[3]);
    ov[2] = packrnd(bf2f((unsigned short)v[4]) * sb[0] / cb[0],
                    bf2f((unsigned short)v[5]) * sb[1] / cb[1]);
    ov[3] = packrnd(bf2f((unsigned short)v[6]) * sb[2] / cb[2],
                    bf2f((unsigned short)v[7]) * sb[3] / cb[3]);
    *(uint4v*)p = ov;
}

// Assemble PV A-frag in registers from swapped-QK outputs.
// Inputs: Sa = scores for j-half0 (lane(il,g) holds j=4g+r, i=il),
//         Sb = j-half1. Output: lane(il,g) holds P[i=il][j=8g..8g+7] as short8.
static __device__ __forceinline__ short8 frag_dance(f32x4 Sa, f32x4 Sb) {
    unsigned A0 = packrnd(__builtin_amdgcn_exp2f(Sa[0]), __builtin_amdgcn_exp2f(Sa[1]));
    unsigned A1 = packrnd(__builtin_amdgcn_exp2f(Sa[2]), __builtin_amdgcn_exp2f(Sa[3]));
    unsigned B0 = packrnd(__builtin_amdgcn_exp2f(Sb[0]), __builtin_amdgcn_exp2f(Sb[1]));
    unsigned B1 = packrnd(__builtin_amdgcn_exp2f(Sb[2]), __builtin_amdgcn_exp2f(Sb[3]));
    uint2v r1 = __builtin_amdgcn_permlane32_swap(A0, B0, false, false);
    uint2v r2 = __builtin_amdgcn_permlane16_swap(r1[0], r1[1], false, false); // dw0, dw2
    uint2v r3 = __builtin_amdgcn_permlane32_swap(A1, B1, false, false);
    uint2v r4 = __builtin_amdgcn_permlane16_swap(r3[0], r3[1], false, false); // dw1, dw3
    uint4v pu;
    pu[0] = r2[0]; pu[1] = r4[0]; pu[2] = r2[1]; pu[3] = r4[1];
    return __builtin_bit_cast(short8, pu);
}

// ---- pass 2: Vpart[z][h][i][d] (bf16) = sum_{j in chunk} 2^(S2_ij) * V'[j,d] ----
// grid (64, NH, CH), 128-thr blocks: block = i-tile 64 (4 Q-frags/wave);
// wave w covers j in [w*256, w*256+256); fully unrolled 8-iter pipeline.
__global__ __launch_bounds__(128) void k_pass2(const unsigned short* __restrict__ Qp,
                                               const unsigned short* __restrict__ Kp,
                                               const unsigned short* __restrict__ VpT,
                                               unsigned short* __restrict__ Vpb) {
    __shared__ __align__(16) float comb[64 * 36];   // stride 36 floats: conflict-free
    int w = threadIdx.x >> 6, l = threadIdx.x & 63;
    int il = l & 15, g = l >> 4;
    int h = blockIdx.y;
    int i0 = blockIdx.x * 64;
    int jbeg = blockIdx.z * JSPAN + w * (JSPAN / 2);
    const unsigned short* Qh = Qp + (size_t)h * N * HD;
    const unsigned short* Kh = Kp + ((size_t)h * N + jbeg) * HD;
    const unsigned short* Vh = VpT + (size_t)h * HD * N + jbeg;
    short8 Qf[4];
#pragma unroll
    for (int q = 0; q < 4; ++q)
        Qf[q] = *(const short8*)(Qh + (size_t)(i0 + q * 16 + il) * HD + g * 8);
    f32x4 z = {0.f, 0.f, 0.f, 0.f};
    f32x4 acc[4][2];
#pragma unroll
    for (int q = 0; q < 4; ++q) { acc[q][0] = z; acc[q][1] = z; }
    // prologue: load jb = 0 operands
    short8 K0 = *(const short8*)(Kh + (size_t)il * HD + g * 8);
    short8 K1 = *(const short8*)(Kh + (size_t)(16 + il) * HD + g * 8);
    short8 V0 = *(const short8*)(Vh + (size_t)il * N + g * 8);
    short8 V1 = *(const short8*)(Vh + (size_t)(16 + il) * N + g * 8);
#pragma unroll
    for (int it = 0; it < 8; ++it) {
        int jb = it * 32;
        short8 cK0 = K0, cK1 = K1, cV0 = V0, cV1 = V1;
        int jn = jb + 32;   // unconditional prefetch; over-read discarded / lands in ws
        K0 = *(const short8*)(Kh + (size_t)(jn + il) * HD + g * 8);
        K1 = *(const short8*)(Kh + (size_t)(jn + 16 + il) * HD + g * 8);
        V0 = *(const short8*)(Vh + (size_t)il * N + jn + g * 8);
        V1 = *(const short8*)(Vh + (size_t)(16 + il) * N + jn + g * 8);
#pragma unroll
        for (int q = 0; q < 4; ++q) {
            // swapped QK: lane(il,g) gets S[j=4g+r][i=il]
            f32x4 SA = __builtin_amdgcn_mfma_f32_16x16x32_bf16(cK0, Qf[q], z, 0, 0, 0);
            f32x4 SB = __builtin_amdgcn_mfma_f32_16x16x32_bf16(cK1, Qf[q], z, 0, 0, 0);
            short8 Pa = frag_dance(SA, SB);
            acc[q][0] = __builtin_amdgcn_mfma_f32_16x16x32_bf16(Pa, cV0, acc[q][0], 0, 0, 0);
            acc[q][1] = __builtin_amdgcn_mfma_f32_16x16x32_bf16(Pa, cV1, acc[q][1], 0, 0, 0);
        }
    }
    // combine the two waves' partials, store bf16
    if (w == 1) {
#pragma unroll
        for (int q = 0; q < 4; ++q) {
            *(f32x4*)(comb + l * 36 + q * 8)     = acc[q][0];
            *(f32x4*)(comb + l * 36 + q * 8 + 4) = acc[q][1];
        }
    }
    __syncthreads();
    if (w == 0) {
        unsigned short* Vout = Vpb + (size_t)(blockIdx.z * NH + h) * N * HD;
#pragma unroll
        for (int q = 0; q < 4; ++q) {
            f32x4 o0 = *(const f32x4*)(comb + l * 36 + q * 8);
            f32x4 o1 = *(const f32x4*)(comb + l * 36 + q * 8 + 4);
#pragma unroll
            for (int r = 0; r < 4; ++r) {
                int ia = i0 + q * 16 + g * 4 + r;
                Vout[(size_t)ia * HD + il]      = f2bf(acc[q][0][r] + o0[r]);
                Vout[(size_t)ia * HD + 16 + il] = f2bf(acc[q][1][r] + o1[r]);
            }
        }
    }
}

// ---- layernorm: sum CH bf16 partials (layout [ch][h][i][d]), normalize ----
__global__ __launch_bounds__(256) void k_ln(const unsigned short* __restrict__ Vpb,
                                            const float* __restrict__ gam,
                                            const float* __restrict__ bet,
                                            float* __restrict__ out) {
    int w = threadIdx.x >> 6, l = threadIdx.x & 63;
    int i = blockIdx.x * 4 + w;
    int h = l >> 3, d0 = (l & 7) << 2;   // lane owns channels c = (d0+r)*8 + h
    f32x4 x = {0.f, 0.f, 0.f, 0.f};
#pragma unroll
    for (int c = 0; c < CH; ++c) {
        short4v v = *(const short4v*)(Vpb + ((size_t)(c * NH + h) * N + i) * HD + d0);
        x[0] += bf2f((unsigned short)v[0]); x[1] += bf2f((unsigned short)v[1]);
        x[2] += bf2f((unsigned short)v[2]); x[3] += bf2f((unsigned short)v[3]);
    }
    float s1 = x[0] + x[1] + x[2] + x[3];
    float s2 = x[0] * x[0] + x[1] * x[1] + x[2] * x[2] + x[3] * x[3];
#pragma unroll
    for (int off = 1; off < 64; off <<= 1) {
        s1 += __shfl_xor(s1, off);
        s2 += __shfl_xor(s2, off);
    }
    float mu = s1 * (1.f / 256.f);
    float var = s2 * (1.f / 256.f) - mu * mu;
    float rs = rsqrtf(var + 1e-3f);
#pragma unroll
    for (int r = 0; r < 4; ++r) {
        int c = (d0 + r) * 8 + h;
        out[(size_t)i * HID + c] = (x[r] - mu) * rs * gam[c] + bet[c];
    }
}

extern "C" void kernel_launch(void* const* d_in, const int* in_sizes, int n_in,
                              void* d_out, int out_size, void* d_ws, size_t ws_size,
                              hipStream_t stream) {
    const float* feat = (const float*)d_in[0];
    const float* Wq   = (const float*)d_in[1];
    const float* bq   = (const float*)d_in[2];
    const float* Wkv  = (const float*)d_in[3];
    const float* bkv  = (const float*)d_in[4];
    const float* Weg  = (const float*)d_in[5];
    const float* beg  = (const float*)d_in[6];
    const float* ln_g = (const float*)d_in[7];
    const float* ln_b = (const float*)d_in[8];
    float* out = (float*)d_out;

    char* ws = (char*)d_ws;
    unsigned short* Qp    = (unsigned short*)(ws + 0);                     // 2 MB
    unsigned short* Kp    = (unsigned short*)(ws + (2u << 20));            // 2 MB
    unsigned short* VpT   = (unsigned short*)(ws + (4u << 20));            // 2 MB
    unsigned short* featb = (unsigned short*)(ws + (6u << 20));            // 2 MB
    unsigned short* WbT   = (unsigned short*)(ws + (8u << 20));            // 0.4 MB
    float* bC   = (float*)(ws + (8u << 20) + (512u << 10));                // 3 KB
    float* sigG = (float*)(ws + (8u << 20) + (528u << 10));                // 128 KB
    float* colS = (float*)(ws + (8u << 20) + (656u << 10));                // 128 KB
    unsigned short* Vpb = (unsigned short*)(ws + (9u << 20));              // CH*2 MB bf16

    k_prep<<<dim3(1024 + NC), 256, 0, stream>>>(feat, Wq, Wkv, Weg, bq, bkv, beg,
                                                featb, WbT, bC, colS);
    k_proj<<<dim3(49, 64), 256, 0, stream>>>(featb, WbT, bC, Qp, Kp, VpT, sigG);
    k_pass1<<<dim3(16, NH, 16), 256, 0, stream>>>(Qp, Kp, colS);
    k_vprep<<<dim3(512), 256, 0, stream>>>(VpT, sigG, colS);
    k_pass2<<<dim3(64, NH, CH), 128, 0, stream>>>(Qp, Kp, VpT, Vpb);
    k_ln<<<dim3(1024), 256, 0, stream>>>(Vpb, ln_g, ln_b, out);
}

// Round 11
// 102.921 us; speedup vs baseline: 1.0822x; 1.0116x over previous
//
#include <hip/hip_runtime.h>
#include <hip/hip_bf16.h>

#define N 4096
#define HID 256
#define NH 8
#define HD 32
#define NC 784    // 256 Q | 256 K | 256 V | 16 EG
#define CH 8      // j-chunks (ws >= 41 MB proven)
#define JSPAN (N / CH)

typedef __attribute__((ext_vector_type(8))) short short8;
typedef __attribute__((ext_vector_type(4))) short short4v;
typedef __attribute__((ext_vector_type(4))) float f32x4;
typedef __attribute__((ext_vector_type(2))) unsigned int uint2v;
typedef __attribute__((ext_vector_type(4))) unsigned int uint4v;

// Q scale = (1/sqrt(32)) * log2(e): folds softmax temp AND exp->exp2 conversion
#define QSCALE 0.25503482f

static __device__ __forceinline__ unsigned short f2bf(float f) {
    union { float f; unsigned u; } v; v.f = f;
    unsigned r = v.u + 0x7fff + ((v.u >> 16) & 1);
    return (unsigned short)(r >> 16);
}
static __device__ __forceinline__ float bf2f(unsigned short u) {
    union { unsigned u; float f; } v; v.u = ((unsigned)u) << 16; return v.f;
}
// branchless RNE pack: dst.lo = bf16(a), dst.hi = bf16(b). ~6 VALU, proven r10.
static __device__ __forceinline__ unsigned packrnd(float a, float b) {
    unsigned ua = __builtin_bit_cast(unsigned, a);
    unsigned ub = __builtin_bit_cast(unsigned, b);
    ua = ua + 0x7fffu + ((ua >> 16) & 1u);
    ub = ub + 0x7fffu + ((ub >> 16) & 1u);
    return (ua >> 16) | (ub & 0xffff0000u);
}

// ---- fused prep: feat->bf16 (blocks 0..1023) | WbT/bC build + colS zero ----
__global__ void k_prep(const float* __restrict__ feat, const float* __restrict__ Wq,
                       const float* __restrict__ Wkv, const float* __restrict__ Weg,
                       const float* __restrict__ bq, const float* __restrict__ bkv,
                       const float* __restrict__ beg, unsigned short* __restrict__ featb,
                       unsigned short* __restrict__ WbT, float* __restrict__ bC,
                       float* __restrict__ colS) {
    int bx = blockIdx.x;
    if (bx < 1024) {
        int t = bx * 256 + threadIdx.x;
        float4 v = ((const float4*)feat)[t];
        short4v o;
        o[0] = (short)f2bf(v.x); o[1] = (short)f2bf(v.y);
        o[2] = (short)f2bf(v.z); o[3] = (short)f2bf(v.w);
        ((short4v*)featb)[t] = o;
    } else {
        int c = bx - 1024, k = threadIdx.x;
        float w, b;
        if (c < 256)      { w = Wq[k * 256 + c];          b = bq[c]; }
        else if (c < 768) { w = Wkv[k * 512 + (c - 256)]; b = bkv[c - 256]; }
        else              { w = Weg[k * 16 + (c - 768)];  b = beg[c - 768]; }
        WbT[c * 256 + k] = f2bf(w);
        if (k == 0) bC[c] = b;
        if (c < 128) colS[c * 256 + k] = 0.f;
    }
}

// ---- projection GEMM: [4096,256]x[256,784]; scatter into packed layouts ----
__global__ __launch_bounds__(256) void k_proj(const unsigned short* __restrict__ featb,
                                              const unsigned short* __restrict__ WbT,
                                              const float* __restrict__ bC,
                                              unsigned short* __restrict__ Qp,
                                              unsigned short* __restrict__ Kp,
                                              unsigned short* __restrict__ VpT,
                                              float* __restrict__ sigG) {
    int w = threadIdx.x >> 6, l = threadIdx.x & 63;
    int il = l & 15, g = l >> 4;
    int c0 = blockIdx.x * 16;
    int i0 = (blockIdx.y * 4 + w) * 16;
    const short8* Arow = (const short8*)(featb + (size_t)(i0 + il) * HID);
    const short8* Brow = (const short8*)(WbT + (size_t)(c0 + il) * HID);
    f32x4 acc = {0.f, 0.f, 0.f, 0.f};
#pragma unroll
    for (int k0 = 0; k0 < HID; k0 += 32) {
        short8 a = Arow[(k0 >> 3) + g];
        short8 b = Brow[(k0 >> 3) + g];
        acc = __builtin_amdgcn_mfma_f32_16x16x32_bf16(a, b, acc, 0, 0, 0);
    }
    int c = c0 + il;
    float bias = bC[c];
#pragma unroll
    for (int r = 0; r < 4; ++r) {
        int i = i0 + g * 4 + r;
        float val = acc[r] + bias;
        if (c < 256) {
            int h = c & 7, d = c >> 3;
            Qp[((size_t)h * N + i) * HD + d] = f2bf(val * QSCALE);
        } else if (c < 512) {
            int cc = c - 256, h = cc & 7, d = cc >> 3;
            Kp[((size_t)h * N + i) * HD + d] = f2bf(val);
        } else if (c < 768) {
            int cc = c - 512, h = cc & 7, d = cc >> 3;
            VpT[((size_t)h * HD + d) * N + i] = f2bf(val);
        } else {
            int cc = c - 768;
            if (cc >= 8) sigG[(size_t)(cc - 8) * N + i] = 1.f / (1.f + __expf(-val));
        }
    }
}

// ---- pass 1: colS[j,h] += sum_i 2^(S2_ij); j-tile 64 resident, i-chunk 256 ----
// grid (16, NH, 16): x*4+w = j-tile of 64 (4 K-frags), z = i-chunk of 256
__global__ __launch_bounds__(256) void k_pass1(const unsigned short* __restrict__ Qp,
                                               const unsigned short* __restrict__ Kp,
                                               float* __restrict__ colS) {
    int w = threadIdx.x >> 6, l = threadIdx.x & 63;
    int il = l & 15, g = l >> 4;
    int h = blockIdx.y;
    int j0 = (blockIdx.x * 4 + w) * 64;
    const unsigned short* Kh = Kp + (size_t)h * N * HD;
    short8 Kf[4];
#pragma unroll
    for (int t = 0; t < 4; ++t)
        Kf[t] = *(const short8*)(Kh + (size_t)(j0 + 16 * t + il) * HD + g * 8);
    const unsigned short* Qh = Qp + (size_t)h * N * HD;
    f32x4 z = {0.f, 0.f, 0.f, 0.f};
    float s[4] = {0.f, 0.f, 0.f, 0.f};
    int ibeg = blockIdx.z * 256;
    short8 Qa = *(const short8*)(Qh + (size_t)(ibeg + il) * HD + g * 8);
    short8 Qb = *(const short8*)(Qh + (size_t)(ibeg + 16 + il) * HD + g * 8);
#pragma unroll 2
    for (int it = 0; it < 8; ++it) {
        int i0 = ibeg + it * 32;
        short8 cQa = Qa, cQb = Qb;
        int in = i0 + 32;   // unconditional prefetch; last over-read lands in ws (safe)
        Qa = *(const short8*)(Qh + (size_t)(in + il) * HD + g * 8);
        Qb = *(const short8*)(Qh + (size_t)(in + 16 + il) * HD + g * 8);
        __builtin_amdgcn_sched_barrier(0);   // pin prefetch above compute
#pragma unroll
        for (int t = 0; t < 4; ++t) {
            f32x4 Sa = __builtin_amdgcn_mfma_f32_16x16x32_bf16(cQa, Kf[t], z, 0, 0, 0);
            f32x4 Sb = __builtin_amdgcn_mfma_f32_16x16x32_bf16(cQb, Kf[t], z, 0, 0, 0);
            s[t] += ((__builtin_amdgcn_exp2f(Sa[0]) + __builtin_amdgcn_exp2f(Sa[1]))
                   + (__builtin_amdgcn_exp2f(Sa[2]) + __builtin_amdgcn_exp2f(Sa[3])))
                  + ((__builtin_amdgcn_exp2f(Sb[0]) + __builtin_amdgcn_exp2f(Sb[1]))
                   + (__builtin_amdgcn_exp2f(Sb[2]) + __builtin_amdgcn_exp2f(Sb[3])));
        }
    }
#pragma unroll
    for (int t = 0; t < 4; ++t) {
        s[t] += __shfl_xor(s[t], 16);
        s[t] += __shfl_xor(s[t], 32);
    }
    if (g == 0) {
#pragma unroll
        for (int t = 0; t < 4; ++t)
            atomicAdd(&colS[(size_t)h * N + j0 + 16 * t + il], s[t]);
    }
}

// ---- V-prescale (in place): V'[h][d][j] = V * sigG[h][j] / colS[h][j] ----
__global__ void k_vprep(unsigned short* __restrict__ VpT,
                        const float* __restrict__ sigG,
                        const float* __restrict__ colS) {
    int row = blockIdx.x >> 1;
    int j0 = ((blockIdx.x & 1) * 256 + threadIdx.x) * 8;
    int h = row >> 5;
    unsigned short* p = VpT + (size_t)row * N + j0;
    short8 v = *(short8*)p;
    const float* sg = sigG + (size_t)h * N + j0;
    const float* cs = colS + (size_t)h * N + j0;
    f32x4 sa = *(const f32x4*)sg, sb = *(const f32x4*)(sg + 4);
    f32x4 ca = *(const f32x4*)cs, cb = *(const f32x4*)(cs + 4);
    uint4v ov;
    ov[0] = packrnd(bf2f((unsigned short)v[0]) * sa[0] / ca[0],
                    bf2f((unsigned short)v[1]) * sa[1] / ca[1]);
    ov[1] = packrnd(bf2f((unsigned short)v[2]) * sa[2] / ca[2],
                    bf2f((unsigned short)v[3]) * sa[3] / ca[3]);
    ov[2] = packrnd(bf2f((unsigned short)v[4]) * sb[0] / cb[0],
                    bf2f((unsigned short)v[5]) * sb[1] / cb[1]);
    ov[3] = packrnd(bf2f((unsigned short)v[6]) * sb[2] / cb[2],
                    bf2f((unsigned short)v[7]) * sb[3] / cb[3]);
    *(uint4v*)p = ov;
}

// Assemble PV A-frag in registers from swapped-QK outputs (proven r10).
static __device__ __forceinline__ short8 frag_dance(f32x4 Sa, f32x4 Sb) {
    unsigned A0 = packrnd(__builtin_amdgcn_exp2f(Sa[0]), __builtin_amdgcn_exp2f(Sa[1]));
    unsigned A1 = packrnd(__builtin_amdgcn_exp2f(Sa[2]), __builtin_amdgcn_exp2f(Sa[3]));
    unsigned B0 = packrnd(__builtin_amdgcn_exp2f(Sb[0]), __builtin_amdgcn_exp2f(Sb[1]));
    unsigned B1 = packrnd(__builtin_amdgcn_exp2f(Sb[2]), __builtin_amdgcn_exp2f(Sb[3]));
    uint2v r1 = __builtin_amdgcn_permlane32_swap(A0, B0, false, false);
    uint2v r2 = __builtin_amdgcn_permlane16_swap(r1[0], r1[1], false, false); // dw0, dw2
    uint2v r3 = __builtin_amdgcn_permlane32_swap(A1, B1, false, false);
    uint2v r4 = __builtin_amdgcn_permlane16_swap(r3[0], r3[1], false, false); // dw1, dw3
    uint4v pu;
    pu[0] = r2[0]; pu[1] = r4[0]; pu[2] = r2[1]; pu[3] = r4[1];
    return __builtin_bit_cast(short8, pu);
}

// ---- pass 2: Vpb[z][h][i][d] (bf16) = sum_{j in chunk} 2^(S2_ij) * V'[j,d] ----
// grid (32, NH, CH), 128-thr blocks: wave w owns i-tile [bx*128+64w, +64).
// Each wave: full chunk j-span (16 iters), 1-deep prefetch + sched_barrier pin.
__global__ __launch_bounds__(128) void k_pass2(const unsigned short* __restrict__ Qp,
                                               const unsigned short* __restrict__ Kp,
                                               const unsigned short* __restrict__ VpT,
                                               unsigned short* __restrict__ Vpb) {
    int w = threadIdx.x >> 6, l = threadIdx.x & 63;
    int il = l & 15, g = l >> 4;
    int h = blockIdx.y;
    int i0 = blockIdx.x * 128 + w * 64;
    int jbeg = blockIdx.z * JSPAN;
    const unsigned short* Qh = Qp + (size_t)h * N * HD;
    const unsigned short* Kh = Kp + ((size_t)h * N + jbeg) * HD;
    const unsigned short* Vh = VpT + (size_t)h * HD * N + jbeg;
    short8 Qf[4];
#pragma unroll
    for (int q = 0; q < 4; ++q)
        Qf[q] = *(const short8*)(Qh + (size_t)(i0 + q * 16 + il) * HD + g * 8);
    f32x4 z = {0.f, 0.f, 0.f, 0.f};
    f32x4 acc[4][2];
#pragma unroll
    for (int q = 0; q < 4; ++q) { acc[q][0] = z; acc[q][1] = z; }
    // prologue: load jb = 0 operands
    short8 K0 = *(const short8*)(Kh + (size_t)il * HD + g * 8);
    short8 K1 = *(const short8*)(Kh + (size_t)(16 + il) * HD + g * 8);
    short8 V0 = *(const short8*)(Vh + (size_t)il * N + g * 8);
    short8 V1 = *(const short8*)(Vh + (size_t)(16 + il) * N + g * 8);
#pragma unroll 2
    for (int it = 0; it < 16; ++it) {
        int jb = it * 32;
        short8 cK0 = K0, cK1 = K1, cV0 = V0, cV1 = V1;
        int jn = jb + 32;   // unconditional prefetch; over-read lands in ws (safe)
        K0 = *(const short8*)(Kh + (size_t)(jn + il) * HD + g * 8);
        K1 = *(const short8*)(Kh + (size_t)(jn + 16 + il) * HD + g * 8);
        V0 = *(const short8*)(Vh + (size_t)il * N + jn + g * 8);
        V1 = *(const short8*)(Vh + (size_t)(16 + il) * N + jn + g * 8);
        __builtin_amdgcn_sched_barrier(0);   // pin prefetch above compute
#pragma unroll
        for (int q = 0; q < 4; ++q) {
            // swapped QK: lane(il,g) gets S[j=4g+r][i=il]
            f32x4 SA = __builtin_amdgcn_mfma_f32_16x16x32_bf16(cK0, Qf[q], z, 0, 0, 0);
            f32x4 SB = __builtin_amdgcn_mfma_f32_16x16x32_bf16(cK1, Qf[q], z, 0, 0, 0);
            short8 Pa = frag_dance(SA, SB);
            acc[q][0] = __builtin_amdgcn_mfma_f32_16x16x32_bf16(Pa, cV0, acc[q][0], 0, 0, 0);
            acc[q][1] = __builtin_amdgcn_mfma_f32_16x16x32_bf16(Pa, cV1, acc[q][1], 0, 0, 0);
        }
    }
    unsigned short* Vout = Vpb + (size_t)(blockIdx.z * NH + h) * N * HD;
#pragma unroll
    for (int q = 0; q < 4; ++q) {
#pragma unroll
        for (int r = 0; r < 4; ++r) {
            int ia = i0 + q * 16 + g * 4 + r;
            Vout[(size_t)ia * HD + il]      = f2bf(acc[q][0][r]);
            Vout[(size_t)ia * HD + 16 + il] = f2bf(acc[q][1][r]);
        }
    }
}

// ---- layernorm: sum CH bf16 partials (layout [ch][h][i][d]), normalize ----
__global__ __launch_bounds__(256) void k_ln(const unsigned short* __restrict__ Vpb,
                                            const float* __restrict__ gam,
                                            const float* __restrict__ bet,
                                            float* __restrict__ out) {
    int w = threadIdx.x >> 6, l = threadIdx.x & 63;
    int i = blockIdx.x * 4 + w;
    int h = l >> 3, d0 = (l & 7) << 2;   // lane owns channels c = (d0+r)*8 + h
    f32x4 x = {0.f, 0.f, 0.f, 0.f};
#pragma unroll
    for (int c = 0; c < CH; ++c) {
        short4v v = *(const short4v*)(Vpb + ((size_t)(c * NH + h) * N + i) * HD + d0);
        x[0] += bf2f((unsigned short)v[0]); x[1] += bf2f((unsigned short)v[1]);
        x[2] += bf2f((unsigned short)v[2]); x[3] += bf2f((unsigned short)v[3]);
    }
    float s1 = x[0] + x[1] + x[2] + x[3];
    float s2 = x[0] * x[0] + x[1] * x[1] + x[2] * x[2] + x[3] * x[3];
#pragma unroll
    for (int off = 1; off < 64; off <<= 1) {
        s1 += __shfl_xor(s1, off);
        s2 += __shfl_xor(s2, off);
    }
    float mu = s1 * (1.f / 256.f);
    float var = s2 * (1.f / 256.f) - mu * mu;
    float rs = rsqrtf(var + 1e-3f);
#pragma unroll
    for (int r = 0; r < 4; ++r) {
        int c = (d0 + r) * 8 + h;
        out[(size_t)i * HID + c] = (x[r] - mu) * rs * gam[c] + bet[c];
    }
}

extern "C" void kernel_launch(void* const* d_in, const int* in_sizes, int n_in,
                              void* d_out, int out_size, void* d_ws, size_t ws_size,
                              hipStream_t stream) {
    const float* feat = (const float*)d_in[0];
    const float* Wq   = (const float*)d_in[1];
    const float* bq   = (const float*)d_in[2];
    const float* Wkv  = (const float*)d_in[3];
    const float* bkv  = (const float*)d_in[4];
    const float* Weg  = (const float*)d_in[5];
    const float* beg  = (const float*)d_in[6];
    const float* ln_g = (const float*)d_in[7];
    const float* ln_b = (const float*)d_in[8];
    float* out = (float*)d_out;

    char* ws = (char*)d_ws;
    unsigned short* Qp    = (unsigned short*)(ws + 0);                     // 2 MB
    unsigned short* Kp    = (unsigned short*)(ws + (2u << 20));            // 2 MB
    unsigned short* VpT   = (unsigned short*)(ws + (4u << 20));            // 2 MB
    unsigned short* featb = (unsigned short*)(ws + (6u << 20));            // 2 MB
    unsigned short* WbT   = (unsigned short*)(ws + (8u << 20));            // 0.4 MB
    float* bC   = (float*)(ws + (8u << 20) + (512u << 10));                // 3 KB
    float* sigG = (float*)(ws + (8u << 20) + (528u << 10));                // 128 KB
    float* colS = (float*)(ws + (8u << 20) + (656u << 10));                // 128 KB
    unsigned short* Vpb = (unsigned short*)(ws + (9u << 20));              // CH*2 MB bf16

    k_prep<<<dim3(1024 + NC), 256, 0, stream>>>(feat, Wq, Wkv, Weg, bq, bkv, beg,
                                                featb, WbT, bC, colS);
    k_proj<<<dim3(49, 64), 256, 0, stream>>>(featb, WbT, bC, Qp, Kp, VpT, sigG);
    k_pass1<<<dim3(16, NH, 16), 256, 0, stream>>>(Qp, Kp, colS);
    k_vprep<<<dim3(512), 256, 0, stream>>>(VpT, sigG, colS);
    k_pass2<<<dim3(32, NH, CH), 128, 0, stream>>>(Qp, Kp, VpT, Vpb);
    k_ln<<<dim3(1024), 256, 0, stream>>>(Vpb, ln_g, ln_b, out);
}

// Round 12
// 101.255 us; speedup vs baseline: 1.1000x; 1.0165x over previous
//
#include <hip/hip_runtime.h>
#include <hip/hip_bf16.h>

#define N 4096
#define HID 256
#define NH 8
#define HD 32
#define NC 784    // 256 Q | 256 K | 256 V | 16 EG
#define CH 16     // j-chunks; Vpb = CH*2MB -> ws total 41 MB (proven bound)
#define JSPAN (N / CH)

typedef __attribute__((ext_vector_type(8))) short short8;
typedef __attribute__((ext_vector_type(4))) short short4v;
typedef __attribute__((ext_vector_type(4))) float f32x4;
typedef __attribute__((ext_vector_type(2))) unsigned int uint2v;
typedef __attribute__((ext_vector_type(4))) unsigned int uint4v;

// Q scale = (1/sqrt(32)) * log2(e): folds softmax temp AND exp->exp2 conversion
#define QSCALE 0.25503482f

static __device__ __forceinline__ unsigned short f2bf(float f) {
    union { float f; unsigned u; } v; v.f = f;
    unsigned r = v.u + 0x7fff + ((v.u >> 16) & 1);
    return (unsigned short)(r >> 16);
}
static __device__ __forceinline__ float bf2f(unsigned short u) {
    union { unsigned u; float f; } v; v.u = ((unsigned)u) << 16; return v.f;
}
// 3-VALU round-half-up pack: lo16 = bf16(a), hi16 = bf16(b).
// v_perm_b32 byte-select: dst bytes = {b.b3, b.b2, a.b3, a.b2} (sel 0x07060302,
// src1 = a holds bytes 0-3). Half-up vs RNE differs only on exact ties.
static __device__ __forceinline__ unsigned packhu(float a, float b) {
    unsigned ua = __builtin_bit_cast(unsigned, a) + 0x8000u;
    unsigned ub = __builtin_bit_cast(unsigned, b) + 0x8000u;
    return __builtin_amdgcn_perm(ub, ua, 0x07060302u);
}

// ---- fused prep: feat->bf16 (blocks 0..1023) | WbT/bC build + colS zero ----
__global__ void k_prep(const float* __restrict__ feat, const float* __restrict__ Wq,
                       const float* __restrict__ Wkv, const float* __restrict__ Weg,
                       const float* __restrict__ bq, const float* __restrict__ bkv,
                       const float* __restrict__ beg, unsigned short* __restrict__ featb,
                       unsigned short* __restrict__ WbT, float* __restrict__ bC,
                       float* __restrict__ colS) {
    int bx = blockIdx.x;
    if (bx < 1024) {
        int t = bx * 256 + threadIdx.x;
        float4 v = ((const float4*)feat)[t];
        short4v o;
        o[0] = (short)f2bf(v.x); o[1] = (short)f2bf(v.y);
        o[2] = (short)f2bf(v.z); o[3] = (short)f2bf(v.w);
        ((short4v*)featb)[t] = o;
    } else {
        int c = bx - 1024, k = threadIdx.x;
        float w, b;
        if (c < 256)      { w = Wq[k * 256 + c];          b = bq[c]; }
        else if (c < 768) { w = Wkv[k * 512 + (c - 256)]; b = bkv[c - 256]; }
        else              { w = Weg[k * 16 + (c - 768)];  b = beg[c - 768]; }
        WbT[c * 256 + k] = f2bf(w);
        if (k == 0) bC[c] = b;
        if (c < 128) colS[c * 256 + k] = 0.f;
    }
}

// ---- projection GEMM: [4096,256]x[256,784]; scatter into packed layouts ----
__global__ __launch_bounds__(256) void k_proj(const unsigned short* __restrict__ featb,
                                              const unsigned short* __restrict__ WbT,
                                              const float* __restrict__ bC,
                                              unsigned short* __restrict__ Qp,
                                              unsigned short* __restrict__ Kp,
                                              unsigned short* __restrict__ VpT,
                                              float* __restrict__ sigG) {
    int w = threadIdx.x >> 6, l = threadIdx.x & 63;
    int il = l & 15, g = l >> 4;
    int c0 = blockIdx.x * 16;
    int i0 = (blockIdx.y * 4 + w) * 16;
    const short8* Arow = (const short8*)(featb + (size_t)(i0 + il) * HID);
    const short8* Brow = (const short8*)(WbT + (size_t)(c0 + il) * HID);
    f32x4 acc = {0.f, 0.f, 0.f, 0.f};
#pragma unroll
    for (int k0 = 0; k0 < HID; k0 += 32) {
        short8 a = Arow[(k0 >> 3) + g];
        short8 b = Brow[(k0 >> 3) + g];
        acc = __builtin_amdgcn_mfma_f32_16x16x32_bf16(a, b, acc, 0, 0, 0);
    }
    int c = c0 + il;
    float bias = bC[c];
#pragma unroll
    for (int r = 0; r < 4; ++r) {
        int i = i0 + g * 4 + r;
        float val = acc[r] + bias;
        if (c < 256) {
            int h = c & 7, d = c >> 3;
            Qp[((size_t)h * N + i) * HD + d] = f2bf(val * QSCALE);
        } else if (c < 512) {
            int cc = c - 256, h = cc & 7, d = cc >> 3;
            Kp[((size_t)h * N + i) * HD + d] = f2bf(val);
        } else if (c < 768) {
            int cc = c - 512, h = cc & 7, d = cc >> 3;
            VpT[((size_t)h * HD + d) * N + i] = f2bf(val);
        } else {
            int cc = c - 768;
            if (cc >= 8) sigG[(size_t)(cc - 8) * N + i] = 1.f / (1.f + __expf(-val));
        }
    }
}

// ---- pass 1: colS[j,h] += sum_i 2^(S2_ij); j-tile 64 resident, i-chunk 128 ----
// grid (16, NH, 32): x*4+w = j-tile of 64 (4 K-frags), z = i-chunk of 128
__global__ __launch_bounds__(256) void k_pass1(const unsigned short* __restrict__ Qp,
                                               const unsigned short* __restrict__ Kp,
                                               float* __restrict__ colS) {
    int w = threadIdx.x >> 6, l = threadIdx.x & 63;
    int il = l & 15, g = l >> 4;
    int h = blockIdx.y;
    int j0 = (blockIdx.x * 4 + w) * 64;
    const unsigned short* Kh = Kp + (size_t)h * N * HD;
    short8 Kf[4];
#pragma unroll
    for (int t = 0; t < 4; ++t)
        Kf[t] = *(const short8*)(Kh + (size_t)(j0 + 16 * t + il) * HD + g * 8);
    const unsigned short* Qh = Qp + (size_t)h * N * HD;
    f32x4 z = {0.f, 0.f, 0.f, 0.f};
    float s[4] = {0.f, 0.f, 0.f, 0.f};
    int ibeg = blockIdx.z * 128;
    short8 Qa = *(const short8*)(Qh + (size_t)(ibeg + il) * HD + g * 8);
    short8 Qb = *(const short8*)(Qh + (size_t)(ibeg + 16 + il) * HD + g * 8);
#pragma unroll 2
    for (int it = 0; it < 4; ++it) {
        int i0 = ibeg + it * 32;
        short8 cQa = Qa, cQb = Qb;
        int in = i0 + 32;   // unconditional prefetch; last over-read lands in ws (safe)
        Qa = *(const short8*)(Qh + (size_t)(in + il) * HD + g * 8);
        Qb = *(const short8*)(Qh + (size_t)(in + 16 + il) * HD + g * 8);
        __builtin_amdgcn_sched_barrier(0);   // pin prefetch above compute
#pragma unroll
        for (int t = 0; t < 4; ++t) {
            f32x4 Sa = __builtin_amdgcn_mfma_f32_16x16x32_bf16(cQa, Kf[t], z, 0, 0, 0);
            f32x4 Sb = __builtin_amdgcn_mfma_f32_16x16x32_bf16(cQb, Kf[t], z, 0, 0, 0);
            s[t] += ((__builtin_amdgcn_exp2f(Sa[0]) + __builtin_amdgcn_exp2f(Sa[1]))
                   + (__builtin_amdgcn_exp2f(Sa[2]) + __builtin_amdgcn_exp2f(Sa[3])))
                  + ((__builtin_amdgcn_exp2f(Sb[0]) + __builtin_amdgcn_exp2f(Sb[1]))
                   + (__builtin_amdgcn_exp2f(Sb[2]) + __builtin_amdgcn_exp2f(Sb[3])));
        }
    }
#pragma unroll
    for (int t = 0; t < 4; ++t) {
        s[t] += __shfl_xor(s[t], 16);
        s[t] += __shfl_xor(s[t], 32);
    }
    if (g == 0) {
#pragma unroll
        for (int t = 0; t < 4; ++t)
            atomicAdd(&colS[(size_t)h * N + j0 + 16 * t + il], s[t]);
    }
}

// ---- V-prescale (in place): V'[h][d][j] = V * sigG[h][j] / colS[h][j] ----
__global__ void k_vprep(unsigned short* __restrict__ VpT,
                        const float* __restrict__ sigG,
                        const float* __restrict__ colS) {
    int row = blockIdx.x >> 1;
    int j0 = ((blockIdx.x & 1) * 256 + threadIdx.x) * 8;
    int h = row >> 5;
    unsigned short* p = VpT + (size_t)row * N + j0;
    short8 v = *(short8*)p;
    const float* sg = sigG + (size_t)h * N + j0;
    const float* cs = colS + (size_t)h * N + j0;
    f32x4 sa = *(const f32x4*)sg, sb = *(const f32x4*)(sg + 4);
    f32x4 ca = *(const f32x4*)cs, cb = *(const f32x4*)(cs + 4);
    uint4v ov;
    ov[0] = packhu(bf2f((unsigned short)v[0]) * sa[0] / ca[0],
                   bf2f((unsigned short)v[1]) * sa[1] / ca[1]);
    ov[1] = packhu(bf2f((unsigned short)v[2]) * sa[2] / ca[2],
                   bf2f((unsigned short)v[3]) * sa[3] / ca[3]);
    ov[2] = packhu(bf2f((unsigned short)v[4]) * sb[0] / cb[0],
                   bf2f((unsigned short)v[5]) * sb[1] / cb[1]);
    ov[3] = packhu(bf2f((unsigned short)v[6]) * sb[2] / cb[2],
                   bf2f((unsigned short)v[7]) * sb[3] / cb[3]);
    *(uint4v*)p = ov;
}

// Assemble PV A-frag in registers from swapped-QK outputs (layout proven r10).
static __device__ __forceinline__ short8 frag_dance(f32x4 Sa, f32x4 Sb) {
    unsigned A0 = packhu(__builtin_amdgcn_exp2f(Sa[0]), __builtin_amdgcn_exp2f(Sa[1]));
    unsigned A1 = packhu(__builtin_amdgcn_exp2f(Sa[2]), __builtin_amdgcn_exp2f(Sa[3]));
    unsigned B0 = packhu(__builtin_amdgcn_exp2f(Sb[0]), __builtin_amdgcn_exp2f(Sb[1]));
    unsigned B1 = packhu(__builtin_amdgcn_exp2f(Sb[2]), __builtin_amdgcn_exp2f(Sb[3]));
    uint2v r1 = __builtin_amdgcn_permlane32_swap(A0, B0, false, false);
    uint2v r2 = __builtin_amdgcn_permlane16_swap(r1[0], r1[1], false, false); // dw0, dw2
    uint2v r3 = __builtin_amdgcn_permlane32_swap(A1, B1, false, false);
    uint2v r4 = __builtin_amdgcn_permlane16_swap(r3[0], r3[1], false, false); // dw1, dw3
    uint4v pu;
    pu[0] = r2[0]; pu[1] = r4[0]; pu[2] = r2[1]; pu[3] = r4[1];
    return __builtin_bit_cast(short8, pu);
}

// ---- pass 2: Vpb[z][h][i][d] (bf16) = sum_{j in chunk} 2^(S2_ij) * V'[j,d] ----
// grid (32, NH, CH), 128-thr blocks: wave w owns i-tile [bx*128+64w, +64).
// Each wave: chunk j-span 256 (8 iters), 1-deep prefetch + sched_barrier pin.
__global__ __launch_bounds__(128) void k_pass2(const unsigned short* __restrict__ Qp,
                                               const unsigned short* __restrict__ Kp,
                                               const unsigned short* __restrict__ VpT,
                                               unsigned short* __restrict__ Vpb) {
    int w = threadIdx.x >> 6, l = threadIdx.x & 63;
    int il = l & 15, g = l >> 4;
    int h = blockIdx.y;
    int i0 = blockIdx.x * 128 + w * 64;
    int jbeg = blockIdx.z * JSPAN;
    const unsigned short* Qh = Qp + (size_t)h * N * HD;
    const unsigned short* Kh = Kp + ((size_t)h * N + jbeg) * HD;
    const unsigned short* Vh = VpT + (size_t)h * HD * N + jbeg;
    short8 Qf[4];
#pragma unroll
    for (int q = 0; q < 4; ++q)
        Qf[q] = *(const short8*)(Qh + (size_t)(i0 + q * 16 + il) * HD + g * 8);
    f32x4 z = {0.f, 0.f, 0.f, 0.f};
    f32x4 acc[4][2];
#pragma unroll
    for (int q = 0; q < 4; ++q) { acc[q][0] = z; acc[q][1] = z; }
    // prologue: load jb = 0 operands
    short8 K0 = *(const short8*)(Kh + (size_t)il * HD + g * 8);
    short8 K1 = *(const short8*)(Kh + (size_t)(16 + il) * HD + g * 8);
    short8 V0 = *(const short8*)(Vh + (size_t)il * N + g * 8);
    short8 V1 = *(const short8*)(Vh + (size_t)(16 + il) * N + g * 8);
#pragma unroll 2
    for (int it = 0; it < 8; ++it) {
        int jb = it * 32;
        short8 cK0 = K0, cK1 = K1, cV0 = V0, cV1 = V1;
        int jn = jb + 32;   // unconditional prefetch; over-read lands in ws (safe)
        K0 = *(const short8*)(Kh + (size_t)(jn + il) * HD + g * 8);
        K1 = *(const short8*)(Kh + (size_t)(jn + 16 + il) * HD + g * 8);
        V0 = *(const short8*)(Vh + (size_t)il * N + jn + g * 8);
        V1 = *(const short8*)(Vh + (size_t)(16 + il) * N + jn + g * 8);
        __builtin_amdgcn_sched_barrier(0);   // pin prefetch above compute
#pragma unroll
        for (int q = 0; q < 4; ++q) {
            // swapped QK: lane(il,g) gets S[j=4g+r][i=il]
            f32x4 SA = __builtin_amdgcn_mfma_f32_16x16x32_bf16(cK0, Qf[q], z, 0, 0, 0);
            f32x4 SB = __builtin_amdgcn_mfma_f32_16x16x32_bf16(cK1, Qf[q], z, 0, 0, 0);
            short8 Pa = frag_dance(SA, SB);
            acc[q][0] = __builtin_amdgcn_mfma_f32_16x16x32_bf16(Pa, cV0, acc[q][0], 0, 0, 0);
            acc[q][1] = __builtin_amdgcn_mfma_f32_16x16x32_bf16(Pa, cV1, acc[q][1], 0, 0, 0);
        }
    }
    unsigned short* Vout = Vpb + (size_t)(blockIdx.z * NH + h) * N * HD;
#pragma unroll
    for (int q = 0; q < 4; ++q) {
#pragma unroll
        for (int r = 0; r < 4; ++r) {
            int ia = i0 + q * 16 + g * 4 + r;
            Vout[(size_t)ia * HD + il]      = f2bf(acc[q][0][r]);
            Vout[(size_t)ia * HD + 16 + il] = f2bf(acc[q][1][r]);
        }
    }
}

// ---- layernorm: sum CH bf16 partials (layout [ch][h][i][d]), normalize ----
__global__ __launch_bounds__(256) void k_ln(const unsigned short* __restrict__ Vpb,
                                            const float* __restrict__ gam,
                                            const float* __restrict__ bet,
                                            float* __restrict__ out) {
    int w = threadIdx.x >> 6, l = threadIdx.x & 63;
    int i = blockIdx.x * 4 + w;
    int h = l >> 3, d0 = (l & 7) << 2;   // lane owns channels c = (d0+r)*8 + h
    f32x4 x = {0.f, 0.f, 0.f, 0.f};
#pragma unroll
    for (int c = 0; c < CH; ++c) {
        short4v v = *(const short4v*)(Vpb + ((size_t)(c * NH + h) * N + i) * HD + d0);
        x[0] += bf2f((unsigned short)v[0]); x[1] += bf2f((unsigned short)v[1]);
        x[2] += bf2f((unsigned short)v[2]); x[3] += bf2f((unsigned short)v[3]);
    }
    float s1 = x[0] + x[1] + x[2] + x[3];
    float s2 = x[0] * x[0] + x[1] * x[1] + x[2] * x[2] + x[3] * x[3];
#pragma unroll
    for (int off = 1; off < 64; off <<= 1) {
        s1 += __shfl_xor(s1, off);
        s2 += __shfl_xor(s2, off);
    }
    float mu = s1 * (1.f / 256.f);
    float var = s2 * (1.f / 256.f) - mu * mu;
    float rs = rsqrtf(var + 1e-3f);
#pragma unroll
    for (int r = 0; r < 4; ++r) {
        int c = (d0 + r) * 8 + h;
        out[(size_t)i * HID + c] = (x[r] - mu) * rs * gam[c] + bet[c];
    }
}

extern "C" void kernel_launch(void* const* d_in, const int* in_sizes, int n_in,
                              void* d_out, int out_size, void* d_ws, size_t ws_size,
                              hipStream_t stream) {
    const float* feat = (const float*)d_in[0];
    const float* Wq   = (const float*)d_in[1];
    const float* bq   = (const float*)d_in[2];
    const float* Wkv  = (const float*)d_in[3];
    const float* bkv  = (const float*)d_in[4];
    const float* Weg  = (const float*)d_in[5];
    const float* beg  = (const float*)d_in[6];
    const float* ln_g = (const float*)d_in[7];
    const float* ln_b = (const float*)d_in[8];
    float* out = (float*)d_out;

    char* ws = (char*)d_ws;
    unsigned short* Qp    = (unsigned short*)(ws + 0);                     // 2 MB
    unsigned short* Kp    = (unsigned short*)(ws + (2u << 20));            // 2 MB
    unsigned short* VpT   = (unsigned short*)(ws + (4u << 20));            // 2 MB
    unsigned short* featb = (unsigned short*)(ws + (6u << 20));            // 2 MB
    unsigned short* WbT   = (unsigned short*)(ws + (8u << 20));            // 0.4 MB
    float* bC   = (float*)(ws + (8u << 20) + (512u << 10));                // 3 KB
    float* sigG = (float*)(ws + (8u << 20) + (528u << 10));                // 128 KB
    float* colS = (float*)(ws + (8u << 20) + (656u << 10));                // 128 KB
    unsigned short* Vpb = (unsigned short*)(ws + (9u << 20));              // CH*2 MB = 32 MB

    k_prep<<<dim3(1024 + NC), 256, 0, stream>>>(feat, Wq, Wkv, Weg, bq, bkv, beg,
                                                featb, WbT, bC, colS);
    k_proj<<<dim3(49, 64), 256, 0, stream>>>(featb, WbT, bC, Qp, Kp, VpT, sigG);
    k_pass1<<<dim3(16, NH, 32), 256, 0, stream>>>(Qp, Kp, colS);
    k_vprep<<<dim3(512), 256, 0, stream>>>(VpT, sigG, colS);
    k_pass2<<<dim3(32, NH, CH), 128, 0, stream>>>(Qp, Kp, VpT, Vpb);
    k_ln<<<dim3(1024), 256, 0, stream>>>(Vpb, ln_g, ln_b, out);
}

// Round 13
// 100.297 us; speedup vs baseline: 1.1105x; 1.0095x over previous
//
#include <hip/hip_runtime.h>
#include <hip/hip_bf16.h>

#define N 4096
#define HID 256
#define NH 8
#define HD 32
#define NC 784    // 256 Q | 256 K | 256 V | 16 EG
#define CH 16     // j-chunks; Vpb = CH*2MB
#define JSPAN (N / CH)

typedef __attribute__((ext_vector_type(8))) short short8;
typedef __attribute__((ext_vector_type(4))) short short4v;
typedef __attribute__((ext_vector_type(4))) float f32x4;
typedef __attribute__((ext_vector_type(2))) unsigned int uint2v;
typedef __attribute__((ext_vector_type(4))) unsigned int uint4v;

// Q scale = (1/sqrt(32)) * log2(e): folds softmax temp AND exp->exp2 conversion
#define QSCALE 0.25503482f

static __device__ __forceinline__ unsigned short f2bf(float f) {
    union { float f; unsigned u; } v; v.f = f;
    unsigned r = v.u + 0x7fff + ((v.u >> 16) & 1);
    return (unsigned short)(r >> 16);
}
static __device__ __forceinline__ float bf2f(unsigned short u) {
    union { unsigned u; float f; } v; v.u = ((unsigned)u) << 16; return v.f;
}
// 3-VALU round-half-up pack: lo16 = bf16(a), hi16 = bf16(b). Proven r12.
static __device__ __forceinline__ unsigned packhu(float a, float b) {
    unsigned ua = __builtin_bit_cast(unsigned, a) + 0x8000u;
    unsigned ub = __builtin_bit_cast(unsigned, b) + 0x8000u;
    return __builtin_amdgcn_perm(ub, ua, 0x07060302u);
}

// ---- fused prep: feat->bf16 (blocks 0..1023) | WbT/bC build + colS zero ----
__global__ void k_prep(const float* __restrict__ feat, const float* __restrict__ Wq,
                       const float* __restrict__ Wkv, const float* __restrict__ Weg,
                       const float* __restrict__ bq, const float* __restrict__ bkv,
                       const float* __restrict__ beg, unsigned short* __restrict__ featb,
                       unsigned short* __restrict__ WbT, float* __restrict__ bC,
                       float* __restrict__ colS) {
    int bx = blockIdx.x;
    if (bx < 1024) {
        int t = bx * 256 + threadIdx.x;
        float4 v = ((const float4*)feat)[t];
        short4v o;
        o[0] = (short)f2bf(v.x); o[1] = (short)f2bf(v.y);
        o[2] = (short)f2bf(v.z); o[3] = (short)f2bf(v.w);
        ((short4v*)featb)[t] = o;
    } else {
        int c = bx - 1024, k = threadIdx.x;
        float w, b;
        if (c < 256)      { w = Wq[k * 256 + c];          b = bq[c]; }
        else if (c < 768) { w = Wkv[k * 512 + (c - 256)]; b = bkv[c - 256]; }
        else              { w = Weg[k * 16 + (c - 768)];  b = beg[c - 768]; }
        WbT[c * 256 + k] = f2bf(w);
        if (k == 0) bC[c] = b;
        if (c < 128) colS[c * 256 + k] = 0.f;
    }
}

// ---- projection GEMM: [4096,256]x[256,784]; scatter into packed layouts ----
__global__ __launch_bounds__(256) void k_proj(const unsigned short* __restrict__ featb,
                                              const unsigned short* __restrict__ WbT,
                                              const float* __restrict__ bC,
                                              unsigned short* __restrict__ Qp,
                                              unsigned short* __restrict__ Kp,
                                              unsigned short* __restrict__ VpT,
                                              float* __restrict__ sigG) {
    int w = threadIdx.x >> 6, l = threadIdx.x & 63;
    int il = l & 15, g = l >> 4;
    int c0 = blockIdx.x * 16;
    int i0 = (blockIdx.y * 4 + w) * 16;
    const short8* Arow = (const short8*)(featb + (size_t)(i0 + il) * HID);
    const short8* Brow = (const short8*)(WbT + (size_t)(c0 + il) * HID);
    f32x4 acc = {0.f, 0.f, 0.f, 0.f};
#pragma unroll
    for (int k0 = 0; k0 < HID; k0 += 32) {
        short8 a = Arow[(k0 >> 3) + g];
        short8 b = Brow[(k0 >> 3) + g];
        acc = __builtin_amdgcn_mfma_f32_16x16x32_bf16(a, b, acc, 0, 0, 0);
    }
    int c = c0 + il;
    float bias = bC[c];
#pragma unroll
    for (int r = 0; r < 4; ++r) {
        int i = i0 + g * 4 + r;
        float val = acc[r] + bias;
        if (c < 256) {
            int h = c & 7, d = c >> 3;
            Qp[((size_t)h * N + i) * HD + d] = f2bf(val * QSCALE);
        } else if (c < 512) {
            int cc = c - 256, h = cc & 7, d = cc >> 3;
            Kp[((size_t)h * N + i) * HD + d] = f2bf(val);
        } else if (c < 768) {
            int cc = c - 512, h = cc & 7, d = cc >> 3;
            VpT[((size_t)h * HD + d) * N + i] = f2bf(val);
        } else {
            int cc = c - 768;
            if (cc >= 8) sigG[(size_t)(cc - 8) * N + i] = 1.f / (1.f + __expf(-val));
        }
    }
}

// ---- pass 1: colS[j,h] += sum_i 2^(S2_ij); 2-deep Q prefetch ----
// grid (16, NH, 32): x*4+w = j-tile of 64 (4 K-frags), z = i-chunk of 128
__global__ __launch_bounds__(256) void k_pass1(const unsigned short* __restrict__ Qp,
                                               const unsigned short* __restrict__ Kp,
                                               float* __restrict__ colS) {
    int w = threadIdx.x >> 6, l = threadIdx.x & 63;
    int il = l & 15, g = l >> 4;
    int h = blockIdx.y;
    int j0 = (blockIdx.x * 4 + w) * 64;
    const unsigned short* Kh = Kp + (size_t)h * N * HD;
    short8 Kf[4];
#pragma unroll
    for (int t = 0; t < 4; ++t)
        Kf[t] = *(const short8*)(Kh + (size_t)(j0 + 16 * t + il) * HD + g * 8);
    const unsigned short* Qh = Qp + (size_t)h * N * HD;
    f32x4 z = {0.f, 0.f, 0.f, 0.f};
    float s[4] = {0.f, 0.f, 0.f, 0.f};
    int ibeg = blockIdx.z * 128;
    // 2-deep prologue (iters 0 and 1)
    short8 Qa0 = *(const short8*)(Qh + (size_t)(ibeg + il) * HD + g * 8);
    short8 Qb0 = *(const short8*)(Qh + (size_t)(ibeg + 16 + il) * HD + g * 8);
    short8 Qa1 = *(const short8*)(Qh + (size_t)(ibeg + 32 + il) * HD + g * 8);
    short8 Qb1 = *(const short8*)(Qh + (size_t)(ibeg + 48 + il) * HD + g * 8);
#pragma unroll
    for (int it = 0; it < 4; ++it) {
        int i0 = ibeg + it * 32;
        short8 cQa = Qa0, cQb = Qb0;
        Qa0 = Qa1; Qb0 = Qb1;
        int in = i0 + 64;   // unconditional 2-ahead prefetch; over-read stays in ws
        Qa1 = *(const short8*)(Qh + (size_t)(in + il) * HD + g * 8);
        Qb1 = *(const short8*)(Qh + (size_t)(in + 16 + il) * HD + g * 8);
        __builtin_amdgcn_sched_barrier(0);   // pin prefetch above compute
#pragma unroll
        for (int t = 0; t < 4; ++t) {
            f32x4 Sa = __builtin_amdgcn_mfma_f32_16x16x32_bf16(cQa, Kf[t], z, 0, 0, 0);
            f32x4 Sb = __builtin_amdgcn_mfma_f32_16x16x32_bf16(cQb, Kf[t], z, 0, 0, 0);
            s[t] += ((__builtin_amdgcn_exp2f(Sa[0]) + __builtin_amdgcn_exp2f(Sa[1]))
                   + (__builtin_amdgcn_exp2f(Sa[2]) + __builtin_amdgcn_exp2f(Sa[3])))
                  + ((__builtin_amdgcn_exp2f(Sb[0]) + __builtin_amdgcn_exp2f(Sb[1]))
                   + (__builtin_amdgcn_exp2f(Sb[2]) + __builtin_amdgcn_exp2f(Sb[3])));
        }
    }
#pragma unroll
    for (int t = 0; t < 4; ++t) {
        s[t] += __shfl_xor(s[t], 16);
        s[t] += __shfl_xor(s[t], 32);
    }
    if (g == 0) {
#pragma unroll
        for (int t = 0; t < 4; ++t)
            atomicAdd(&colS[(size_t)h * N + j0 + 16 * t + il], s[t]);
    }
}

// ---- V-prescale (in place): V'[h][d][j] = V * sigG[h][j] / colS[h][j] ----
__global__ void k_vprep(unsigned short* __restrict__ VpT,
                        const float* __restrict__ sigG,
                        const float* __restrict__ colS) {
    int row = blockIdx.x >> 1;
    int j0 = ((blockIdx.x & 1) * 256 + threadIdx.x) * 8;
    int h = row >> 5;
    unsigned short* p = VpT + (size_t)row * N + j0;
    short8 v = *(short8*)p;
    const float* sg = sigG + (size_t)h * N + j0;
    const float* cs = colS + (size_t)h * N + j0;
    f32x4 sa = *(const f32x4*)sg, sb = *(const f32x4*)(sg + 4);
    f32x4 ca = *(const f32x4*)cs, cb = *(const f32x4*)(cs + 4);
    uint4v ov;
    ov[0] = packhu(bf2f((unsigned short)v[0]) * sa[0] / ca[0],
                   bf2f((unsigned short)v[1]) * sa[1] / ca[1]);
    ov[1] = packhu(bf2f((unsigned short)v[2]) * sa[2] / ca[2],
                   bf2f((unsigned short)v[3]) * sa[3] / ca[3]);
    ov[2] = packhu(bf2f((unsigned short)v[4]) * sb[0] / cb[0],
                   bf2f((unsigned short)v[5]) * sb[1] / cb[1]);
    ov[3] = packhu(bf2f((unsigned short)v[6]) * sb[2] / cb[2],
                   bf2f((unsigned short)v[7]) * sb[3] / cb[3]);
    *(uint4v*)p = ov;
}

// Assemble PV A-frag in registers from swapped-QK outputs (layout proven r10).
static __device__ __forceinline__ short8 frag_dance(f32x4 Sa, f32x4 Sb) {
    unsigned A0 = packhu(__builtin_amdgcn_exp2f(Sa[0]), __builtin_amdgcn_exp2f(Sa[1]));
    unsigned A1 = packhu(__builtin_amdgcn_exp2f(Sa[2]), __builtin_amdgcn_exp2f(Sa[3]));
    unsigned B0 = packhu(__builtin_amdgcn_exp2f(Sb[0]), __builtin_amdgcn_exp2f(Sb[1]));
    unsigned B1 = packhu(__builtin_amdgcn_exp2f(Sb[2]), __builtin_amdgcn_exp2f(Sb[3]));
    uint2v r1 = __builtin_amdgcn_permlane32_swap(A0, B0, false, false);
    uint2v r2 = __builtin_amdgcn_permlane16_swap(r1[0], r1[1], false, false); // dw0, dw2
    uint2v r3 = __builtin_amdgcn_permlane32_swap(A1, B1, false, false);
    uint2v r4 = __builtin_amdgcn_permlane16_swap(r3[0], r3[1], false, false); // dw1, dw3
    uint4v pu;
    pu[0] = r2[0]; pu[1] = r4[0]; pu[2] = r2[1]; pu[3] = r4[1];
    return __builtin_bit_cast(short8, pu);
}

// ---- pass 2: Vpb[z][h][i][d] (bf16) = sum_{j in chunk} 2^(S2_ij) * V'[j,d] ----
// grid (32, NH, CH), 128-thr blocks: wave w owns i-tile [bx*128+64w, +64).
// 2-deep K/V software pipeline: issue loads for iter k+2, compute iter k.
__global__ __launch_bounds__(128) void k_pass2(const unsigned short* __restrict__ Qp,
                                               const unsigned short* __restrict__ Kp,
                                               const unsigned short* __restrict__ VpT,
                                               unsigned short* __restrict__ Vpb) {
    int w = threadIdx.x >> 6, l = threadIdx.x & 63;
    int il = l & 15, g = l >> 4;
    int h = blockIdx.y;
    int i0 = blockIdx.x * 128 + w * 64;
    int jbeg = blockIdx.z * JSPAN;
    const unsigned short* Qh = Qp + (size_t)h * N * HD;
    const unsigned short* Kh = Kp + ((size_t)h * N + jbeg) * HD;
    const unsigned short* Vh = VpT + (size_t)h * HD * N + jbeg;
    short8 Qf[4];
#pragma unroll
    for (int q = 0; q < 4; ++q)
        Qf[q] = *(const short8*)(Qh + (size_t)(i0 + q * 16 + il) * HD + g * 8);
    f32x4 z = {0.f, 0.f, 0.f, 0.f};
    f32x4 acc[4][2];
#pragma unroll
    for (int q = 0; q < 4; ++q) { acc[q][0] = z; acc[q][1] = z; }
    // 2-deep prologue: iters 0 and 1 operands in flight
    short8 K0a = *(const short8*)(Kh + (size_t)il * HD + g * 8);
    short8 K1a = *(const short8*)(Kh + (size_t)(16 + il) * HD + g * 8);
    short8 V0a = *(const short8*)(Vh + (size_t)il * N + g * 8);
    short8 V1a = *(const short8*)(Vh + (size_t)(16 + il) * N + g * 8);
    short8 K0b = *(const short8*)(Kh + (size_t)(32 + il) * HD + g * 8);
    short8 K1b = *(const short8*)(Kh + (size_t)(48 + il) * HD + g * 8);
    short8 V0b = *(const short8*)(Vh + (size_t)il * N + 32 + g * 8);
    short8 V1b = *(const short8*)(Vh + (size_t)(16 + il) * N + 32 + g * 8);
#pragma unroll
    for (int it = 0; it < 8; ++it) {
        int jb = it * 32;
        short8 cK0 = K0a, cK1 = K1a, cV0 = V0a, cV1 = V1a;
        K0a = K0b; K1a = K1b; V0a = V0b; V1a = V1b;
        int jn = jb + 64;   // 2-ahead unconditional prefetch; over-read stays in ws
        K0b = *(const short8*)(Kh + (size_t)(jn + il) * HD + g * 8);
        K1b = *(const short8*)(Kh + (size_t)(jn + 16 + il) * HD + g * 8);
        V0b = *(const short8*)(Vh + (size_t)il * N + jn + g * 8);
        V1b = *(const short8*)(Vh + (size_t)(16 + il) * N + jn + g * 8);
        __builtin_amdgcn_sched_barrier(0);   // pin prefetch above compute
#pragma unroll
        for (int q = 0; q < 4; ++q) {
            // swapped QK: lane(il,g) gets S[j=4g+r][i=il]
            f32x4 SA = __builtin_amdgcn_mfma_f32_16x16x32_bf16(cK0, Qf[q], z, 0, 0, 0);
            f32x4 SB = __builtin_amdgcn_mfma_f32_16x16x32_bf16(cK1, Qf[q], z, 0, 0, 0);
            short8 Pa = frag_dance(SA, SB);
            acc[q][0] = __builtin_amdgcn_mfma_f32_16x16x32_bf16(Pa, cV0, acc[q][0], 0, 0, 0);
            acc[q][1] = __builtin_amdgcn_mfma_f32_16x16x32_bf16(Pa, cV1, acc[q][1], 0, 0, 0);
        }
    }
    unsigned short* Vout = Vpb + (size_t)(blockIdx.z * NH + h) * N * HD;
#pragma unroll
    for (int q = 0; q < 4; ++q) {
#pragma unroll
        for (int r = 0; r < 4; ++r) {
            int ia = i0 + q * 16 + g * 4 + r;
            Vout[(size_t)ia * HD + il]      = f2bf(acc[q][0][r]);
            Vout[(size_t)ia * HD + 16 + il] = f2bf(acc[q][1][r]);
        }
    }
}

// ---- layernorm: sum CH bf16 partials (layout [ch][h][i][d]), normalize ----
__global__ __launch_bounds__(256) void k_ln(const unsigned short* __restrict__ Vpb,
                                            const float* __restrict__ gam,
                                            const float* __restrict__ bet,
                                            float* __restrict__ out) {
    int w = threadIdx.x >> 6, l = threadIdx.x & 63;
    int i = blockIdx.x * 4 + w;
    int h = l >> 3, d0 = (l & 7) << 2;   // lane owns channels c = (d0+r)*8 + h
    f32x4 x = {0.f, 0.f, 0.f, 0.f};
#pragma unroll
    for (int c = 0; c < CH; ++c) {
        short4v v = *(const short4v*)(Vpb + ((size_t)(c * NH + h) * N + i) * HD + d0);
        x[0] += bf2f((unsigned short)v[0]); x[1] += bf2f((unsigned short)v[1]);
        x[2] += bf2f((unsigned short)v[2]); x[3] += bf2f((unsigned short)v[3]);
    }
    float s1 = x[0] + x[1] + x[2] + x[3];
    float s2 = x[0] * x[0] + x[1] * x[1] + x[2] * x[2] + x[3] * x[3];
#pragma unroll
    for (int off = 1; off < 64; off <<= 1) {
        s1 += __shfl_xor(s1, off);
        s2 += __shfl_xor(s2, off);
    }
    float mu = s1 * (1.f / 256.f);
    float var = s2 * (1.f / 256.f) - mu * mu;
    float rs = rsqrtf(var + 1e-3f);
#pragma unroll
    for (int r = 0; r < 4; ++r) {
        int c = (d0 + r) * 8 + h;
        out[(size_t)i * HID + c] = (x[r] - mu) * rs * gam[c] + bet[c];
    }
}

extern "C" void kernel_launch(void* const* d_in, const int* in_sizes, int n_in,
                              void* d_out, int out_size, void* d_ws, size_t ws_size,
                              hipStream_t stream) {
    const float* feat = (const float*)d_in[0];
    const float* Wq   = (const float*)d_in[1];
    const float* bq   = (const float*)d_in[2];
    const float* Wkv  = (const float*)d_in[3];
    const float* bkv  = (const float*)d_in[4];
    const float* Weg  = (const float*)d_in[5];
    const float* beg  = (const float*)d_in[6];
    const float* ln_g = (const float*)d_in[7];
    const float* ln_b = (const float*)d_in[8];
    float* out = (float*)d_out;

    char* ws = (char*)d_ws;
    unsigned short* Qp    = (unsigned short*)(ws + 0);                     // 2 MB
    unsigned short* Kp    = (unsigned short*)(ws + (2u << 20));            // 2 MB
    unsigned short* VpT   = (unsigned short*)(ws + (4u << 20));            // 2 MB
    unsigned short* featb = (unsigned short*)(ws + (6u << 20));            // 2 MB
    unsigned short* WbT   = (unsigned short*)(ws + (8u << 20));            // 0.4 MB
    float* bC   = (float*)(ws + (8u << 20) + (512u << 10));                // 3 KB
    float* sigG = (float*)(ws + (8u << 20) + (528u << 10));                // 128 KB
    float* colS = (float*)(ws + (8u << 20) + (656u << 10));                // 128 KB
    unsigned short* Vpb = (unsigned short*)(ws + (9u << 20));              // CH*2 MB = 32 MB

    k_prep<<<dim3(1024 + NC), 256, 0, stream>>>(feat, Wq, Wkv, Weg, bq, bkv, beg,
                                                featb, WbT, bC, colS);
    k_proj<<<dim3(49, 64), 256, 0, stream>>>(featb, WbT, bC, Qp, Kp, VpT, sigG);
    k_pass1<<<dim3(16, NH, 32), 256, 0, stream>>>(Qp, Kp, colS);
    k_vprep<<<dim3(512), 256, 0, stream>>>(VpT, sigG, colS);
    k_pass2<<<dim3(32, NH, CH), 128, 0, stream>>>(Qp, Kp, VpT, Vpb);
    k_ln<<<dim3(1024), 256, 0, stream>>>(Vpb, ln_g, ln_b, out);
}